// Round 5
// baseline (177.341 us; speedup 1.0000x reference)
//
#include <hip/hip_runtime.h>

typedef __attribute__((ext_vector_type(4))) float f32x4;
typedef __attribute__((ext_vector_type(8))) __bf16 bf16x8;
typedef __attribute__((ext_vector_type(4))) __bf16 bf16x4;
typedef __attribute__((ext_vector_type(2))) unsigned int u32x2;

__device__ __forceinline__ u32x2 tr_read(unsigned int byte_addr){
    u32x2 d;
    asm volatile("ds_read_b64_tr_b16 %0, %1" : "=v"(d) : "v"(byte_addr));
    return d;
}
__device__ __forceinline__ bf16x8 frag_cat(u32x2 a, u32x2 b){
    union { u32x2 u[2]; bf16x8 f; } c; c.u[0] = a; c.u[1] = b; return c.f;
}

// ws layout (floats):
//   x1   @ 0       (65536)
//   v    @ 65536   (65536)
//   Q1   @ 131072  (262144)   q@attn_w1 + attn_b1   [1024][256]
//   K1   @ 393216  (262144)   k@attn_w1             [1024][256]
//   W'   @ 655360  (16384)    pos_w2@attn_w1        [64][256]
// total 671744 floats = 2.63 MB

// ---------------------------------------------------------------------------
// Kernel W': W' = pos_w2 @ attn_w1   (64x256, K=64). One block.
// ---------------------------------------------------------------------------
__global__ void ptb_wprime(const float* __restrict__ pos_w2,
                           const float* __restrict__ attn_w1,
                           float* __restrict__ ws)
{
    __shared__ float sW2[4096];
    const int e = threadIdx.x;
    #pragma unroll
    for (int r = 0; r < 16; ++r) sW2[r*256 + e] = pos_w2[r*256 + e];
    __syncthreads();
    float wcol[64];
    #pragma unroll
    for (int dd = 0; dd < 64; ++dd) wcol[dd] = attn_w1[dd*256 + e];
    float* Wp = ws + 655360;
    #pragma unroll 1
    for (int h = 0; h < 64; ++h){
        float acc = 0.f;
        #pragma unroll
        for (int dd = 0; dd < 64; ++dd) acc += sW2[h*64 + dd] * wcol[dd];
        Wp[h*256 + e] = acc;
    }
}

// ---------------------------------------------------------------------------
// Kernel A: x1, v ; Q1 = (x1@q_w)@attn_w1 + attn_b1 ; K1 = (x1@k_w)@attn_w1
// pos passthrough to out.
// ---------------------------------------------------------------------------
__global__ void ptb_precompute(const float* __restrict__ x,
                               const float* __restrict__ pos,
                               const float* __restrict__ prev_w,
                               const float* __restrict__ prev_b,
                               const float* __restrict__ q_w,
                               const float* __restrict__ k_w,
                               const float* __restrict__ v_w,
                               const float* __restrict__ attn_w1,
                               const float* __restrict__ attn_b1,
                               float* __restrict__ ws,
                               float* __restrict__ out)
{
    const int row = blockIdx.x;
    const int d   = threadIdx.x;
    __shared__ float xr[64], x1r[64], qsh[64], ksh[64];
    xr[d] = x[row*64 + d];
    __syncthreads();
    float a = prev_b[d];
    #pragma unroll 16
    for (int c = 0; c < 64; ++c) a += xr[c] * prev_w[c*64 + d];
    x1r[d] = a;
    ws[row*64 + d] = a;
    __syncthreads();
    float qv = 0.f, kv = 0.f, vv = 0.f;
    #pragma unroll 16
    for (int c = 0; c < 64; ++c){
        float t = x1r[c];
        qv += t * q_w[c*64 + d];
        kv += t * k_w[c*64 + d];
        vv += t * v_w[c*64 + d];
    }
    ws[65536 + row*64 + d] = vv;
    qsh[d] = qv; ksh[d] = kv;
    __syncthreads();
    float* Q1 = ws + 131072;
    float* K1 = ws + 393216;
    #pragma unroll 1
    for (int et = 0; et < 4; ++et){
        const int e = et*64 + d;
        float sq = attn_b1[e], sk = 0.f;
        #pragma unroll 16
        for (int c = 0; c < 64; ++c){
            const float wv = attn_w1[c*256 + e];
            sq += qsh[c] * wv;
            sk += ksh[c] * wv;
        }
        Q1[row*256 + e] = sq;
        K1[row*256 + e] = sk;
    }
    const int gid = row*64 + d;
    if (gid < 2*512*3) out[65536 + gid] = pos[gid];
}

// ---------------------------------------------------------------------------
// Kernel B: one block per (b,i). 4 waves. 64-j tiles, sHT halved (32-j).
// Per tile: [B1] A(t+1)->sH1[buf^1] + Bhalf0 ; [bar] Chalf0 ; [bar] Bhalf1 ;
//           [bar] Chalf1.
// GEMM1' : H = relu( h1relu @ W' + (Q1_i - K1_j) )   (h1 read as A-frags
//          straight from sH1 -- no transpose staging needed)
// rpe    : recomputed in stage C as 2 MFMAs (sH1 x pos_w2[:,dch-slice])
// LDS 34KB, targets VGPR<=128 for 4 blocks/CU (m69: waves halve at 128).
// NO launch-bounds min-waves pin (round-1: forced VGPR 84 + spills).
// ---------------------------------------------------------------------------
__global__ __launch_bounds__(256) void ptb_main(
    const float* __restrict__ pos,
    const float* __restrict__ pos_w1, const float* __restrict__ pos_b1,
    const float* __restrict__ pos_w2, const float* __restrict__ pos_b2,
    const float* __restrict__ attn_w2, const float* __restrict__ attn_b2,
    const float* __restrict__ fin_w, const float* __restrict__ fin_b,
    const float* __restrict__ ws, float* __restrict__ out)
{
    const int blk = blockIdx.x;
    const int b   = blk >> 9;
    const int i   = blk & 511;
    const int tid = threadIdx.x;
    const int w   = tid >> 6;
    const int l   = tid & 63;
    const int lg  = l >> 4;
    const int ln  = l & 15;

    // h1 tile (post-relu), XOR-swizzled 16B chunks: [buf][j][h ^ ((j&7)<<3)]
    __shared__ __bf16 sH1[2][64][64];            // 16 KB
    // H^T half-tile for tr_read: [es=e/4][jj][er=e&3][jl=j&15]
    __shared__ __bf16 sHT[64][2][4][16];         // 16 KB
    __shared__ float sPW1[192], sPB1[64], sAGG[64], sPOSI[3];

    const float* x1p = ws;
    const float* vp  = ws + 65536;
    const float* Q1  = ws + 131072;
    const float* K1  = ws + 393216;
    const float* Wp  = ws + 655360;

    if (tid < 64) sPB1[tid] = pos_b1[tid];
    if (tid >= 64 && tid < 256) sPW1[tid - 64] = pos_w1[tid - 64];
    if (tid < 3) sPOSI[tid] = pos[(b*512 + i)*3 + tid];

    const int dch  = w*16 + ln;         // this lane's output channel (GEMM2)
    const int Ew   = w*64;              // this wave's hidden-col base (GEMM1')
    const int swzA = (ln & 7) << 3;     // sH1 h-chunk swizzle (row&7 == ln&7)

    // ---- register-resident weight B-fragments ----
    bf16x8 w1f[2][4];                   // W' frags
    #pragma unroll
    for (int kf = 0; kf < 2; ++kf)
        #pragma unroll
        for (int et = 0; et < 4; ++et)
            #pragma unroll
            for (int ii = 0; ii < 8; ++ii)
                w1f[kf][et][ii] = (__bf16)Wp[(kf*32 + lg*8 + ii)*256 + Ew + et*16 + ln];
    bf16x8 w2f[8];
    #pragma unroll
    for (int kf = 0; kf < 8; ++kf)
        #pragma unroll
        for (int ii = 0; ii < 8; ++ii)
            w2f[kf][ii] = (__bf16)attn_w2[(kf*32 + lg*8 + ii)*64 + dch];
    bf16x8 pwfw[2];                     // pos_w2 frags, this wave's d-slice only
    #pragma unroll
    for (int kf = 0; kf < 2; ++kf)
        #pragma unroll
        for (int ii = 0; ii < 8; ++ii)
            pwfw[kf][ii] = (__bf16)pos_w2[(kf*32 + lg*8 + ii)*64 + dch];

    float Q1b[4];
    #pragma unroll
    for (int et = 0; et < 4; ++et) Q1b[et] = Q1[blk*256 + Ew + et*16 + ln];
    const float pb2v = pos_b2[dch];
    const float b2v  = attn_b2[dch];

    const unsigned sHTb = (unsigned)(unsigned long long)&sHT[0][0][0][0];

    float mrun = -1e30f, srun = 0.f, arun = 0.f;

    // ---- stage A: h1 MLP only (no MFMA, no staging loads) ----
    auto stageA = [&](int j0a){
        const int bufa = (j0a >> 6) & 1;
        const float* pj = &pos[(b*512 + j0a + w*16 + ln)*3];
        const float r0 = sPOSI[0] - pj[0];
        const float r1 = sPOSI[1] - pj[1];
        const float r2 = sPOSI[2] - pj[2];
        #pragma unroll
        for (int kf = 0; kf < 2; ++kf){
            const int hb = kf*32 + lg*8;
            f32x4 wa0 = *(const f32x4*)&sPW1[      hb],   wa1 = *(const f32x4*)&sPW1[      hb+4];
            f32x4 wb0 = *(const f32x4*)&sPW1[ 64 + hb],   wb1 = *(const f32x4*)&sPW1[ 64 + hb+4];
            f32x4 wc0 = *(const f32x4*)&sPW1[128 + hb],   wc1 = *(const f32x4*)&sPW1[128 + hb+4];
            f32x4 bb0 = *(const f32x4*)&sPB1[      hb],   bb1 = *(const f32x4*)&sPB1[      hb+4];
            bf16x8 h1f;
            #pragma unroll
            for (int ii = 0; ii < 4; ++ii){
                float hv0 = bb0[ii] + r0*wa0[ii] + r1*wb0[ii] + r2*wc0[ii];
                float hv1 = bb1[ii] + r0*wa1[ii] + r1*wb1[ii] + r2*wc1[ii];
                h1f[ii]   = (__bf16)fmaxf(hv0, 0.f);
                h1f[ii+4] = (__bf16)fmaxf(hv1, 0.f);
            }
            *(bf16x8*)&sH1[bufa][w*16 + ln][hb ^ swzA] = h1f;
        }
    };

    __syncthreads();
    stageA(0);

    #pragma unroll 1
    for (int t = 0; t < 8; ++t){
        const int j0  = t << 6;
        const int buf = t & 1;
        __syncthreads();                                    // B1
        if (t < 7) stageA(j0 + 64);                         // -> sH1[buf^1]
        #pragma unroll 1
        for (int hb = 0; hb < 2; ++hb){
            // ============== stage B half: GEMM1' ======================
            #pragma unroll
            for (int jj = 0; jj < 2; ++jj){
                const int jrow = hb*32 + jj*16;
                const bf16x8 af0 = *(const bf16x8*)&sH1[buf][jrow + ln][(     lg*8) ^ swzA];
                const bf16x8 af1 = *(const bf16x8*)&sH1[buf][jrow + ln][(32 + lg*8) ^ swzA];
                float kw[4][4];
                #pragma unroll
                for (int et = 0; et < 4; ++et)
                    #pragma unroll
                    for (int ri = 0; ri < 4; ++ri)
                        kw[et][ri] = K1[(b*512 + j0 + jrow + lg*4 + ri)*256 + Ew + et*16 + ln];
                f32x4 accs[4];
                #pragma unroll
                for (int et = 0; et < 4; ++et){
                    f32x4 ci = {Q1b[et]-kw[et][0], Q1b[et]-kw[et][1],
                                Q1b[et]-kw[et][2], Q1b[et]-kw[et][3]};
                    accs[et] = ci;
                }
                __builtin_amdgcn_s_setprio(1);
                #pragma unroll
                for (int et = 0; et < 4; ++et)
                    accs[et] = __builtin_amdgcn_mfma_f32_16x16x32_bf16(af0, w1f[0][et], accs[et], 0, 0, 0);
                #pragma unroll
                for (int et = 0; et < 4; ++et)
                    accs[et] = __builtin_amdgcn_mfma_f32_16x16x32_bf16(af1, w1f[1][et], accs[et], 0, 0, 0);
                __builtin_amdgcn_s_setprio(0);
                #pragma unroll
                for (int et = 0; et < 4; ++et){
                    bf16x4 hp;
                    #pragma unroll
                    for (int ri = 0; ri < 4; ++ri) hp[ri] = (__bf16)fmaxf(accs[et][ri], 0.f);
                    *(bf16x4*)&sHT[w*16 + et*4 + (ln>>2)][jj][ln&3][lg*4] = hp;
                }
            }
            __syncthreads();                                // H half ready
            // ============== stage C half: GEMM2 + rpe + softmax =======
            #pragma unroll
            for (int jj = 0; jj < 2; ++jj){
                const int jrow = hb*32 + jj*16;
                float vvv[4];
                #pragma unroll
                for (int ri = 0; ri < 4; ++ri)
                    vvv[ri] = vp[(b*512 + j0 + jrow + lg*4 + ri)*64 + dch];
                const bf16x8 ra0 = *(const bf16x8*)&sH1[buf][jrow + ln][(     lg*8) ^ swzA];
                const bf16x8 ra1 = *(const bf16x8*)&sH1[buf][jrow + ln][(32 + lg*8) ^ swzA];
                u32x2 h1a[8];
                #pragma unroll
                for (int kf = 0; kf < 4; ++kf){
                    h1a[kf*2]   = tr_read(sHTb + 2u*(((8*kf + 2*lg    )*2 + jj)*64) + ln*8);
                    h1a[kf*2+1] = tr_read(sHTb + 2u*(((8*kf + 2*lg + 1)*2 + jj)*64) + ln*8);
                }
                asm volatile("s_waitcnt lgkmcnt(8)" ::: "memory");
                __builtin_amdgcn_sched_barrier(0);
                f32x4 rc = {pb2v, pb2v, pb2v, pb2v};        // rpe (for v2)
                rc = __builtin_amdgcn_mfma_f32_16x16x32_bf16(ra0, pwfw[0], rc, 0, 0, 0);
                rc = __builtin_amdgcn_mfma_f32_16x16x32_bf16(ra1, pwfw[1], rc, 0, 0, 0);
                u32x2 h1b[8];
                #pragma unroll
                for (int kf = 4; kf < 8; ++kf){
                    h1b[(kf-4)*2]   = tr_read(sHTb + 2u*(((8*kf + 2*lg    )*2 + jj)*64) + ln*8);
                    h1b[(kf-4)*2+1] = tr_read(sHTb + 2u*(((8*kf + 2*lg + 1)*2 + jj)*64) + ln*8);
                }
                asm volatile("s_waitcnt lgkmcnt(8)" ::: "memory");
                __builtin_amdgcn_sched_barrier(0);
                f32x4 a0 = {b2v, b2v, b2v, b2v};
                f32x4 a1 = {0.f, 0.f, 0.f, 0.f};
                __builtin_amdgcn_s_setprio(1);
                a0 = __builtin_amdgcn_mfma_f32_16x16x32_bf16(frag_cat(h1a[0], h1a[1]), w2f[0], a0, 0, 0, 0);
                a1 = __builtin_amdgcn_mfma_f32_16x16x32_bf16(frag_cat(h1a[2], h1a[3]), w2f[1], a1, 0, 0, 0);
                a0 = __builtin_amdgcn_mfma_f32_16x16x32_bf16(frag_cat(h1a[4], h1a[5]), w2f[2], a0, 0, 0, 0);
                a1 = __builtin_amdgcn_mfma_f32_16x16x32_bf16(frag_cat(h1a[6], h1a[7]), w2f[3], a1, 0, 0, 0);
                __builtin_amdgcn_s_setprio(0);
                asm volatile("s_waitcnt lgkmcnt(0)" ::: "memory");
                __builtin_amdgcn_sched_barrier(0);
                __builtin_amdgcn_s_setprio(1);
                a0 = __builtin_amdgcn_mfma_f32_16x16x32_bf16(frag_cat(h1b[0], h1b[1]), w2f[4], a0, 0, 0, 0);
                a1 = __builtin_amdgcn_mfma_f32_16x16x32_bf16(frag_cat(h1b[2], h1b[3]), w2f[5], a1, 0, 0, 0);
                a0 = __builtin_amdgcn_mfma_f32_16x16x32_bf16(frag_cat(h1b[4], h1b[5]), w2f[6], a0, 0, 0, 0);
                a1 = __builtin_amdgcn_mfma_f32_16x16x32_bf16(frag_cat(h1b[6], h1b[7]), w2f[7], a1, 0, 0, 0);
                __builtin_amdgcn_s_setprio(0);
                const f32x4 acc = a0 + a1;
                float tmax = fmaxf(fmaxf(acc[0], acc[1]), fmaxf(acc[2], acc[3]));
                tmax = fmaxf(tmax, __shfl_xor(tmax, 16));
                tmax = fmaxf(tmax, __shfl_xor(tmax, 32));
                const float mnew  = fmaxf(mrun, tmax);
                const float scale = __expf(mrun - mnew);
                srun *= scale; arun *= scale; mrun = mnew;
                #pragma unroll
                for (int ri = 0; ri < 4; ++ri){
                    const float p = __expf(acc[ri] - mnew);
                    srun += p;
                    arun += p * (vvv[ri] + rc[ri]);
                }
            }
            if (hb == 0) __syncthreads();                   // WAR: sHT reuse
        }
        // loop top's B1 covers: sH1[buf] WAR vs A(t+2), sHT WAR vs Bhalf0(t+1)
    }

    arun += __shfl_xor(arun, 16); arun += __shfl_xor(arun, 32);
    srun += __shfl_xor(srun, 16); srun += __shfl_xor(srun, 32);
    if (lg == 0) sAGG[dch] = arun / srun;
    __syncthreads();

    if (tid < 64){
        float a = fin_b[tid] + x1p[blk*64 + tid];
        #pragma unroll 16
        for (int c = 0; c < 64; ++c) a += sAGG[c] * fin_w[c*64 + tid];
        out[blk*64 + tid] = a;
    }
}

// ---------------------------------------------------------------------------
extern "C" void kernel_launch(void* const* d_in, const int* in_sizes, int n_in,
                              void* d_out, int out_size, void* d_ws, size_t ws_size,
                              hipStream_t stream)
{
    const float* x       = (const float*)d_in[0];
    const float* pos     = (const float*)d_in[1];
    const float* prev_w  = (const float*)d_in[2];
    const float* prev_b  = (const float*)d_in[3];
    const float* q_w     = (const float*)d_in[4];
    const float* k_w     = (const float*)d_in[5];
    const float* v_w     = (const float*)d_in[6];
    const float* pos_w1  = (const float*)d_in[7];
    const float* pos_b1  = (const float*)d_in[8];
    const float* pos_w2  = (const float*)d_in[9];
    const float* pos_b2  = (const float*)d_in[10];
    const float* attn_w1 = (const float*)d_in[11];
    const float* attn_b1 = (const float*)d_in[12];
    const float* attn_w2 = (const float*)d_in[13];
    const float* attn_b2 = (const float*)d_in[14];
    const float* fin_w   = (const float*)d_in[15];
    const float* fin_b   = (const float*)d_in[16];
    float* out = (float*)d_out;
    float* ws  = (float*)d_ws;

    ptb_wprime<<<1, 256, 0, stream>>>(pos_w2, attn_w1, ws);
    ptb_precompute<<<1024, 64, 0, stream>>>(x, pos, prev_w, prev_b, q_w, k_w, v_w,
                                            attn_w1, attn_b1, ws, out);
    ptb_main<<<1024, 256, 0, stream>>>(pos, pos_w1, pos_b1, pos_w2, pos_b2,
                                       attn_w2, attn_b2, fin_w, fin_b, ws, out);
}

// Round 6
// 131.676 us; speedup vs baseline: 1.3468x; 1.3468x over previous
//
#include <hip/hip_runtime.h>

typedef __attribute__((ext_vector_type(4))) float f32x4;
typedef __attribute__((ext_vector_type(8))) __bf16 bf16x8;
typedef __attribute__((ext_vector_type(4))) __bf16 bf16x4;
typedef __attribute__((ext_vector_type(2))) unsigned int u32x2;

__device__ __forceinline__ u32x2 tr_read(unsigned int byte_addr){
    u32x2 d;
    asm volatile("ds_read_b64_tr_b16 %0, %1" : "=v"(d) : "v"(byte_addr));
    return d;
}
__device__ __forceinline__ bf16x8 frag_cat(u32x2 a, u32x2 b){
    union { u32x2 u[2]; bf16x8 f; } c; c.u[0] = a; c.u[1] = b; return c.f;
}

// ws layout (floats):
//   x1   @ 0       (65536)
//   q    @ 65536   (65536)
//   k    @ 131072  (65536)
//   vT   @ 196608  (65536)    v transposed [64][1024]
//   Q1   @ 262144  (262144)   q@attn_w1 + attn_b1   [1024][256]
//   K1T  @ 524288  (262144)   (k@attn_w1)^T         [256][1024]
//   W'   @ 786432  (16384)    pos_w2@attn_w1        [64][256]
// total 802816 floats = 3.06 MB

// ---------------------------------------------------------------------------
// Stage 1: x1 = x@prev_w+prev_b ; q/k/v = x1@{q,k,v}_w (v transposed);
// pos passthrough to out. 1024 blocks x 64.
// ---------------------------------------------------------------------------
__global__ void ptb_stage1(const float* __restrict__ x,
                           const float* __restrict__ pos,
                           const float* __restrict__ prev_w,
                           const float* __restrict__ prev_b,
                           const float* __restrict__ q_w,
                           const float* __restrict__ k_w,
                           const float* __restrict__ v_w,
                           float* __restrict__ ws,
                           float* __restrict__ out)
{
    const int row = blockIdx.x;
    const int d   = threadIdx.x;
    __shared__ float xr[64], x1r[64];
    xr[d] = x[row*64 + d];
    __syncthreads();
    float a = prev_b[d];
    #pragma unroll 16
    for (int c = 0; c < 64; ++c) a += xr[c] * prev_w[c*64 + d];
    x1r[d] = a;
    ws[row*64 + d] = a;
    __syncthreads();
    float qv = 0.f, kv = 0.f, vv = 0.f;
    #pragma unroll 16
    for (int c = 0; c < 64; ++c){
        float t = x1r[c];
        qv += t * q_w[c*64 + d];
        kv += t * k_w[c*64 + d];
        vv += t * v_w[c*64 + d];
    }
    ws[ 65536 + row*64 + d] = qv;
    ws[131072 + row*64 + d] = kv;
    ws[196608 + d*1024 + row] = vv;          // vT scatter
    const int gid = row*64 + d;
    if (gid < 2*512*3) out[65536 + gid] = pos[gid];
}

// ---------------------------------------------------------------------------
// Stage 2 (parallel prologue GEMMs, all through attn_w1 columns-in-regs):
//   blocks 0..255 : Q1 rows 4b..4b+3 (row-major) and K1T (transposed)
//   blocks 256..271: W' rows 4(b-256).. (pos_w2 @ attn_w1)
// 272 blocks x 256. Replaces round-5's 1-wave-per-block precompute tail and
// the single-block serial wprime (~65us combined -> target <10us).
// ---------------------------------------------------------------------------
__global__ void ptb_stage2(const float* __restrict__ pos_w2,
                           const float* __restrict__ attn_w1,
                           const float* __restrict__ attn_b1,
                           float* __restrict__ ws)
{
    const int bid = blockIdx.x;
    const int e   = threadIdx.x;
    const float* qp = ws + 65536;
    const float* kp = ws + 131072;
    float* Q1  = ws + 262144;
    float* K1T = ws + 524288;
    float* Wp  = ws + 786432;

    __shared__ float sA[256], sB[256];       // 4 rows x 64 each
    if (bid < 256){
        sA[e] = qp[bid*256 + e];
        sB[e] = kp[bid*256 + e];
    } else {
        sA[e] = pos_w2[(bid - 256)*256 + e];
    }
    __syncthreads();

    float wcol[64];
    #pragma unroll
    for (int c = 0; c < 64; ++c) wcol[c] = attn_w1[c*256 + e];

    if (bid < 256){
        const float bb = attn_b1[e];
        float sq[4], sk[4];
        #pragma unroll
        for (int r = 0; r < 4; ++r){ sq[r] = bb; sk[r] = 0.f; }
        #pragma unroll 16
        for (int c = 0; c < 64; ++c){
            const float wv = wcol[c];
            #pragma unroll
            for (int r = 0; r < 4; ++r){
                sq[r] += sA[r*64 + c] * wv;
                sk[r] += sB[r*64 + c] * wv;
            }
        }
        #pragma unroll
        for (int r = 0; r < 4; ++r) Q1[(bid*4 + r)*256 + e] = sq[r];
        f32x4 kvec = {sk[0], sk[1], sk[2], sk[3]};
        *(f32x4*)&K1T[e*1024 + bid*4] = kvec;
    } else {
        #pragma unroll
        for (int r = 0; r < 4; ++r){
            float s = 0.f;
            #pragma unroll 16
            for (int c = 0; c < 64; ++c) s += sA[r*64 + c] * wcol[c];
            Wp[((bid - 256)*4 + r)*256 + e] = s;
        }
    }
}

// ---------------------------------------------------------------------------
// Kernel B: one block per (b,i). 4 waves. 64-j tiles, sHT halved (32-j).
// Per tile: [B1] A(t+1)->sH1[buf^1] + Bhalf0 ; [bar] Chalf0 ; [bar] Bhalf1 ;
//           [bar] Chalf1.
// GEMM1' : H = relu( h1relu @ W' + (Q1_i - K1_j) )
// rpe    : recomputed in stage C as 2 MFMAs (sH1 x pos_w2[:,dch-slice])
// K1 consumed transposed (f32x4), v consumed transposed (f32x4).
// LDS 34KB, VGPR ~124 -> 4 blocks/CU (m69: waves halve at 128).
// NO launch-bounds min-waves pin (round-1: forced VGPR 84 + spills).
// ---------------------------------------------------------------------------
__global__ __launch_bounds__(256) void ptb_main(
    const float* __restrict__ pos,
    const float* __restrict__ pos_w1, const float* __restrict__ pos_b1,
    const float* __restrict__ pos_w2, const float* __restrict__ pos_b2,
    const float* __restrict__ attn_w2, const float* __restrict__ attn_b2,
    const float* __restrict__ fin_w, const float* __restrict__ fin_b,
    const float* __restrict__ ws, float* __restrict__ out)
{
    const int blk = blockIdx.x;
    const int b   = blk >> 9;
    const int i   = blk & 511;
    const int tid = threadIdx.x;
    const int w   = tid >> 6;
    const int l   = tid & 63;
    const int lg  = l >> 4;
    const int ln  = l & 15;

    // h1 tile (post-relu), XOR-swizzled 16B chunks: [buf][j][h ^ ((j&7)<<3)]
    __shared__ __bf16 sH1[2][64][64];            // 16 KB
    // H^T half-tile for tr_read: [es=e/4][jj][er=e&3][jl=j&15]
    __shared__ __bf16 sHT[64][2][4][16];         // 16 KB
    __shared__ float sPW1[192], sPB1[64], sAGG[64], sPOSI[3];

    const float* x1p = ws;
    const float* vT  = ws + 196608;
    const float* Q1  = ws + 262144;
    const float* K1T = ws + 524288;
    const float* Wp  = ws + 786432;

    if (tid < 64) sPB1[tid] = pos_b1[tid];
    if (tid >= 64 && tid < 256) sPW1[tid - 64] = pos_w1[tid - 64];
    if (tid < 3) sPOSI[tid] = pos[(b*512 + i)*3 + tid];

    const int dch  = w*16 + ln;         // this lane's output channel (GEMM2)
    const int Ew   = w*64;              // this wave's hidden-col base (GEMM1')
    const int swzA = (ln & 7) << 3;     // sH1 h-chunk swizzle (row&7 == ln&7)

    // ---- register-resident weight B-fragments ----
    bf16x8 w1f[2][4];                   // W' frags
    #pragma unroll
    for (int kf = 0; kf < 2; ++kf)
        #pragma unroll
        for (int et = 0; et < 4; ++et)
            #pragma unroll
            for (int ii = 0; ii < 8; ++ii)
                w1f[kf][et][ii] = (__bf16)Wp[(kf*32 + lg*8 + ii)*256 + Ew + et*16 + ln];
    bf16x8 w2f[8];
    #pragma unroll
    for (int kf = 0; kf < 8; ++kf)
        #pragma unroll
        for (int ii = 0; ii < 8; ++ii)
            w2f[kf][ii] = (__bf16)attn_w2[(kf*32 + lg*8 + ii)*64 + dch];
    bf16x8 pwfw[2];                     // pos_w2 frags, this wave's d-slice only
    #pragma unroll
    for (int kf = 0; kf < 2; ++kf)
        #pragma unroll
        for (int ii = 0; ii < 8; ++ii)
            pwfw[kf][ii] = (__bf16)pos_w2[(kf*32 + lg*8 + ii)*64 + dch];

    float Q1b[4];
    #pragma unroll
    for (int et = 0; et < 4; ++et) Q1b[et] = Q1[blk*256 + Ew + et*16 + ln];
    const float pb2v = pos_b2[dch];
    const float b2v  = attn_b2[dch];

    const unsigned sHTb = (unsigned)(unsigned long long)&sHT[0][0][0][0];

    float mrun = -1e30f, srun = 0.f, arun = 0.f;

    // ---- stage A: h1 MLP only (no MFMA, no staging loads) ----
    auto stageA = [&](int j0a){
        const int bufa = (j0a >> 6) & 1;
        const float* pj = &pos[(b*512 + j0a + w*16 + ln)*3];
        const float r0 = sPOSI[0] - pj[0];
        const float r1 = sPOSI[1] - pj[1];
        const float r2 = sPOSI[2] - pj[2];
        #pragma unroll
        for (int kf = 0; kf < 2; ++kf){
            const int hb = kf*32 + lg*8;
            f32x4 wa0 = *(const f32x4*)&sPW1[      hb],   wa1 = *(const f32x4*)&sPW1[      hb+4];
            f32x4 wb0 = *(const f32x4*)&sPW1[ 64 + hb],   wb1 = *(const f32x4*)&sPW1[ 64 + hb+4];
            f32x4 wc0 = *(const f32x4*)&sPW1[128 + hb],   wc1 = *(const f32x4*)&sPW1[128 + hb+4];
            f32x4 bb0 = *(const f32x4*)&sPB1[      hb],   bb1 = *(const f32x4*)&sPB1[      hb+4];
            bf16x8 h1f;
            #pragma unroll
            for (int ii = 0; ii < 4; ++ii){
                float hv0 = bb0[ii] + r0*wa0[ii] + r1*wb0[ii] + r2*wc0[ii];
                float hv1 = bb1[ii] + r0*wa1[ii] + r1*wb1[ii] + r2*wc1[ii];
                h1f[ii]   = (__bf16)fmaxf(hv0, 0.f);
                h1f[ii+4] = (__bf16)fmaxf(hv1, 0.f);
            }
            *(bf16x8*)&sH1[bufa][w*16 + ln][hb ^ swzA] = h1f;
        }
    };

    __syncthreads();
    stageA(0);

    #pragma unroll 1
    for (int t = 0; t < 8; ++t){
        const int j0  = t << 6;
        const int buf = t & 1;
        __syncthreads();                                    // B1
        if (t < 7) stageA(j0 + 64);                         // -> sH1[buf^1]
        #pragma unroll 1
        for (int hb = 0; hb < 2; ++hb){
            // ============== stage B half: GEMM1' ======================
            #pragma unroll
            for (int jj = 0; jj < 2; ++jj){
                const int jrow = hb*32 + jj*16;
                const bf16x8 af0 = *(const bf16x8*)&sH1[buf][jrow + ln][(     lg*8) ^ swzA];
                const bf16x8 af1 = *(const bf16x8*)&sH1[buf][jrow + ln][(32 + lg*8) ^ swzA];
                f32x4 accs[4];
                #pragma unroll
                for (int et = 0; et < 4; ++et){
                    const f32x4 kw4 = *(const f32x4*)&K1T[(Ew + et*16 + ln)*1024
                                                          + b*512 + j0 + jrow + lg*4];
                    const f32x4 qv4 = {Q1b[et], Q1b[et], Q1b[et], Q1b[et]};
                    accs[et] = qv4 - kw4;
                }
                __builtin_amdgcn_s_setprio(1);
                #pragma unroll
                for (int et = 0; et < 4; ++et)
                    accs[et] = __builtin_amdgcn_mfma_f32_16x16x32_bf16(af0, w1f[0][et], accs[et], 0, 0, 0);
                #pragma unroll
                for (int et = 0; et < 4; ++et)
                    accs[et] = __builtin_amdgcn_mfma_f32_16x16x32_bf16(af1, w1f[1][et], accs[et], 0, 0, 0);
                __builtin_amdgcn_s_setprio(0);
                #pragma unroll
                for (int et = 0; et < 4; ++et){
                    bf16x4 hp;
                    #pragma unroll
                    for (int ri = 0; ri < 4; ++ri) hp[ri] = (__bf16)fmaxf(accs[et][ri], 0.f);
                    *(bf16x4*)&sHT[w*16 + et*4 + (ln>>2)][jj][ln&3][lg*4] = hp;
                }
            }
            __syncthreads();                                // H half ready
            // ============== stage C half: GEMM2 + rpe + softmax =======
            #pragma unroll
            for (int jj = 0; jj < 2; ++jj){
                const int jrow = hb*32 + jj*16;
                const f32x4 vv4 = *(const f32x4*)&vT[dch*1024 + b*512 + j0 + jrow + lg*4];
                const bf16x8 ra0 = *(const bf16x8*)&sH1[buf][jrow + ln][(     lg*8) ^ swzA];
                const bf16x8 ra1 = *(const bf16x8*)&sH1[buf][jrow + ln][(32 + lg*8) ^ swzA];
                u32x2 h1a[8];
                #pragma unroll
                for (int kf = 0; kf < 4; ++kf){
                    h1a[kf*2]   = tr_read(sHTb + 2u*(((8*kf + 2*lg    )*2 + jj)*64) + ln*8);
                    h1a[kf*2+1] = tr_read(sHTb + 2u*(((8*kf + 2*lg + 1)*2 + jj)*64) + ln*8);
                }
                asm volatile("s_waitcnt lgkmcnt(8)" ::: "memory");
                __builtin_amdgcn_sched_barrier(0);
                f32x4 rc = {pb2v, pb2v, pb2v, pb2v};        // rpe (for v2)
                rc = __builtin_amdgcn_mfma_f32_16x16x32_bf16(ra0, pwfw[0], rc, 0, 0, 0);
                rc = __builtin_amdgcn_mfma_f32_16x16x32_bf16(ra1, pwfw[1], rc, 0, 0, 0);
                u32x2 h1b[8];
                #pragma unroll
                for (int kf = 4; kf < 8; ++kf){
                    h1b[(kf-4)*2]   = tr_read(sHTb + 2u*(((8*kf + 2*lg    )*2 + jj)*64) + ln*8);
                    h1b[(kf-4)*2+1] = tr_read(sHTb + 2u*(((8*kf + 2*lg + 1)*2 + jj)*64) + ln*8);
                }
                asm volatile("s_waitcnt lgkmcnt(8)" ::: "memory");
                __builtin_amdgcn_sched_barrier(0);
                f32x4 a0 = {b2v, b2v, b2v, b2v};
                f32x4 a1 = {0.f, 0.f, 0.f, 0.f};
                __builtin_amdgcn_s_setprio(1);
                a0 = __builtin_amdgcn_mfma_f32_16x16x32_bf16(frag_cat(h1a[0], h1a[1]), w2f[0], a0, 0, 0, 0);
                a1 = __builtin_amdgcn_mfma_f32_16x16x32_bf16(frag_cat(h1a[2], h1a[3]), w2f[1], a1, 0, 0, 0);
                a0 = __builtin_amdgcn_mfma_f32_16x16x32_bf16(frag_cat(h1a[4], h1a[5]), w2f[2], a0, 0, 0, 0);
                a1 = __builtin_amdgcn_mfma_f32_16x16x32_bf16(frag_cat(h1a[6], h1a[7]), w2f[3], a1, 0, 0, 0);
                __builtin_amdgcn_s_setprio(0);
                asm volatile("s_waitcnt lgkmcnt(0)" ::: "memory");
                __builtin_amdgcn_sched_barrier(0);
                __builtin_amdgcn_s_setprio(1);
                a0 = __builtin_amdgcn_mfma_f32_16x16x32_bf16(frag_cat(h1b[0], h1b[1]), w2f[4], a0, 0, 0, 0);
                a1 = __builtin_amdgcn_mfma_f32_16x16x32_bf16(frag_cat(h1b[2], h1b[3]), w2f[5], a1, 0, 0, 0);
                a0 = __builtin_amdgcn_mfma_f32_16x16x32_bf16(frag_cat(h1b[4], h1b[5]), w2f[6], a0, 0, 0, 0);
                a1 = __builtin_amdgcn_mfma_f32_16x16x32_bf16(frag_cat(h1b[6], h1b[7]), w2f[7], a1, 0, 0, 0);
                __builtin_amdgcn_s_setprio(0);
                const f32x4 acc = a0 + a1;
                float tmax = fmaxf(fmaxf(acc[0], acc[1]), fmaxf(acc[2], acc[3]));
                tmax = fmaxf(tmax, __shfl_xor(tmax, 16));
                tmax = fmaxf(tmax, __shfl_xor(tmax, 32));
                const float mnew  = fmaxf(mrun, tmax);
                const float scale = __expf(mrun - mnew);
                srun *= scale; arun *= scale; mrun = mnew;
                #pragma unroll
                for (int ri = 0; ri < 4; ++ri){
                    const float p = __expf(acc[ri] - mnew);
                    srun += p;
                    arun += p * (vv4[ri] + rc[ri]);
                }
            }
            if (hb == 0) __syncthreads();                   // WAR: sHT reuse
        }
        // loop top's B1 covers: sH1[buf] WAR vs A(t+2), sHT WAR vs Bhalf0(t+1)
    }

    arun += __shfl_xor(arun, 16); arun += __shfl_xor(arun, 32);
    srun += __shfl_xor(srun, 16); srun += __shfl_xor(srun, 32);
    if (lg == 0) sAGG[dch] = arun / srun;
    __syncthreads();

    if (tid < 64){
        float a = fin_b[tid] + x1p[blk*64 + tid];
        #pragma unroll 16
        for (int c = 0; c < 64; ++c) a += sAGG[c] * fin_w[c*64 + tid];
        out[blk*64 + tid] = a;
    }
}

// ---------------------------------------------------------------------------
extern "C" void kernel_launch(void* const* d_in, const int* in_sizes, int n_in,
                              void* d_out, int out_size, void* d_ws, size_t ws_size,
                              hipStream_t stream)
{
    const float* x       = (const float*)d_in[0];
    const float* pos     = (const float*)d_in[1];
    const float* prev_w  = (const float*)d_in[2];
    const float* prev_b  = (const float*)d_in[3];
    const float* q_w     = (const float*)d_in[4];
    const float* k_w     = (const float*)d_in[5];
    const float* v_w     = (const float*)d_in[6];
    const float* pos_w1  = (const float*)d_in[7];
    const float* pos_b1  = (const float*)d_in[8];
    const float* pos_w2  = (const float*)d_in[9];
    const float* pos_b2  = (const float*)d_in[10];
    const float* attn_w1 = (const float*)d_in[11];
    const float* attn_b1 = (const float*)d_in[12];
    const float* attn_w2 = (const float*)d_in[13];
    const float* attn_b2 = (const float*)d_in[14];
    const float* fin_w   = (const float*)d_in[15];
    const float* fin_b   = (const float*)d_in[16];
    float* out = (float*)d_out;
    float* ws  = (float*)d_ws;

    ptb_stage1<<<1024, 64, 0, stream>>>(x, pos, prev_w, prev_b, q_w, k_w, v_w, ws, out);
    ptb_stage2<<<272, 256, 0, stream>>>(pos_w2, attn_w1, attn_b1, ws);
    ptb_main<<<1024, 256, 0, stream>>>(pos, pos_w1, pos_b1, pos_w2, pos_b2,
                                       attn_w2, attn_b2, fin_w, fin_b, ws, out);
}

// Round 7
// 119.947 us; speedup vs baseline: 1.4785x; 1.0978x over previous
//
#include <hip/hip_runtime.h>

typedef __attribute__((ext_vector_type(4))) float f32x4;
typedef __attribute__((ext_vector_type(8))) __bf16 bf16x8;
typedef __attribute__((ext_vector_type(4))) __bf16 bf16x4;
typedef __attribute__((ext_vector_type(2))) unsigned int u32x2;

__device__ __forceinline__ u32x2 tr_read(unsigned int byte_addr){
    u32x2 d;
    asm volatile("ds_read_b64_tr_b16 %0, %1" : "=v"(d) : "v"(byte_addr));
    return d;
}
__device__ __forceinline__ bf16x8 frag_cat(u32x2 a, u32x2 b){
    union { u32x2 u[2]; bf16x8 f; } c; c.u[0] = a; c.u[1] = b; return c.f;
}

// ws layout (floats):
//   x1   @ 0       (65536)
//   v    @ 65536   (65536)    row-major [1024][64]
//   Q1   @ 131072  (262144)   q@attn_w1 + attn_b1   [1024][256]
//   K1   @ 393216  (262144)   k@attn_w1             [1024][256]
//   W'   @ 655360  (16384)    pos_w2@attn_w1        [64][256]
// total 671744 floats = 2.63 MB

// ---------------------------------------------------------------------------
// Fused prologue: 272 blocks x 256.
//   blocks 0..255 : rows 4b..4b+3 : x1,q,k,v (phase 1, q/k stay in LDS) then
//                   Q1 = q@attn_w1+b1, K1 = k@attn_w1 (phase 2, col/thread).
//                   pos passthrough to out.
//   blocks 256..271: W' = pos_w2 @ attn_w1.
// Replaces round-6's stage1+stage2 (q/k never round-trip through global;
// one launch fewer).
// ---------------------------------------------------------------------------
__global__ void ptb_pre(const float* __restrict__ x,
                        const float* __restrict__ pos,
                        const float* __restrict__ prev_w,
                        const float* __restrict__ prev_b,
                        const float* __restrict__ q_w,
                        const float* __restrict__ k_w,
                        const float* __restrict__ v_w,
                        const float* __restrict__ pos_w2,
                        const float* __restrict__ attn_w1,
                        const float* __restrict__ attn_b1,
                        float* __restrict__ ws,
                        float* __restrict__ out)
{
    const int bid = blockIdx.x;
    const int tid = threadIdx.x;
    __shared__ float xr[256], x1r[256], qsh[256], ksh[256];

    float wcol[64];                       // attn_w1 column `tid`
    #pragma unroll
    for (int c = 0; c < 64; ++c) wcol[c] = attn_w1[c*256 + tid];

    if (bid >= 256){
        // W' = pos_w2 @ attn_w1  (rows 4(bid-256)..+3)
        xr[tid] = pos_w2[(bid - 256)*256 + tid];
        __syncthreads();
        float* Wp = ws + 655360;
        #pragma unroll
        for (int r = 0; r < 4; ++r){
            float s = 0.f;
            #pragma unroll 16
            for (int c = 0; c < 64; ++c) s += xr[r*64 + c] * wcol[c];
            Wp[((bid - 256)*4 + r)*256 + tid] = s;
        }
        return;
    }

    const int rr  = tid >> 6, d = tid & 63;
    const int row = bid*4 + rr;
    xr[tid] = x[row*64 + d];
    __syncthreads();
    float a = prev_b[d];
    #pragma unroll 16
    for (int c = 0; c < 64; ++c) a += xr[rr*64 + c] * prev_w[c*64 + d];
    x1r[tid] = a;
    ws[row*64 + d] = a;
    __syncthreads();
    float qv = 0.f, kv = 0.f, vv = 0.f;
    #pragma unroll 16
    for (int c = 0; c < 64; ++c){
        float t = x1r[rr*64 + c];
        qv += t * q_w[c*64 + d];
        kv += t * k_w[c*64 + d];
        vv += t * v_w[c*64 + d];
    }
    ws[65536 + row*64 + d] = vv;
    qsh[tid] = qv; ksh[tid] = kv;
    if (tid < 12) out[65536 + bid*12 + tid] = pos[bid*12 + tid];
    __syncthreads();

    // phase 2: thread `tid` = hidden column e, all 4 rows of this block
    float* Q1 = ws + 131072;
    float* K1 = ws + 393216;
    const float bb = attn_b1[tid];
    float sq[4], sk[4];
    #pragma unroll
    for (int r = 0; r < 4; ++r){ sq[r] = bb; sk[r] = 0.f; }
    #pragma unroll 16
    for (int c = 0; c < 64; ++c){
        const float wv = wcol[c];
        #pragma unroll
        for (int r = 0; r < 4; ++r){
            sq[r] += qsh[r*64 + c] * wv;
            sk[r] += ksh[r*64 + c] * wv;
        }
    }
    #pragma unroll
    for (int r = 0; r < 4; ++r){
        Q1[(bid*4 + r)*256 + tid] = sq[r];
        K1[(bid*4 + r)*256 + tid] = sk[r];
    }
}

// ---------------------------------------------------------------------------
// Kernel B: one block per (b,i). 4 waves. 64-j tiles, sHT halved (32-j).
// Per tile: [B1] A(t+1)->sH1[buf^1] + Bhalf0 ; [bar] Chalf0 ; [bar] Bhalf1 ;
//           [bar] Chalf1.
// GEMM1' : H = relu( h1relu @ W' + (Q1_i - K1_j) )
// rpe    : recomputed in stage C as 2 MFMAs (sH1 x pos_w2[:,dch-slice])
// K1 and v consumed ROW-MAJOR coalesced (round-6's transposed f32x4 loads
// were lane-strided 4KB -> uncoalesced, +5us; reverted to round-5 form).
// LDS 34KB, VGPR ~124 -> 4 blocks/CU (m69: waves halve at 128).
// NO launch-bounds min-waves pin (round-1: forced VGPR 84 + spills).
// ---------------------------------------------------------------------------
__global__ __launch_bounds__(256) void ptb_main(
    const float* __restrict__ pos,
    const float* __restrict__ pos_w1, const float* __restrict__ pos_b1,
    const float* __restrict__ pos_w2, const float* __restrict__ pos_b2,
    const float* __restrict__ attn_w2, const float* __restrict__ attn_b2,
    const float* __restrict__ fin_w, const float* __restrict__ fin_b,
    const float* __restrict__ ws, float* __restrict__ out)
{
    const int blk = blockIdx.x;
    const int b   = blk >> 9;
    const int i   = blk & 511;
    const int tid = threadIdx.x;
    const int w   = tid >> 6;
    const int l   = tid & 63;
    const int lg  = l >> 4;
    const int ln  = l & 15;

    // h1 tile (post-relu), XOR-swizzled 16B chunks: [buf][j][h ^ ((j&7)<<3)]
    __shared__ __bf16 sH1[2][64][64];            // 16 KB
    // H^T half-tile for tr_read: [es=e/4][jj][er=e&3][jl=j&15]
    __shared__ __bf16 sHT[64][2][4][16];         // 16 KB
    __shared__ float sPW1[192], sPB1[64], sAGG[64], sPOSI[3];

    const float* x1p = ws;
    const float* vp  = ws + 65536;
    const float* Q1  = ws + 131072;
    const float* K1  = ws + 393216;
    const float* Wp  = ws + 655360;

    if (tid < 64) sPB1[tid] = pos_b1[tid];
    if (tid >= 64 && tid < 256) sPW1[tid - 64] = pos_w1[tid - 64];
    if (tid < 3) sPOSI[tid] = pos[(b*512 + i)*3 + tid];

    const int dch  = w*16 + ln;         // this lane's output channel (GEMM2)
    const int Ew   = w*64;              // this wave's hidden-col base (GEMM1')
    const int swzA = (ln & 7) << 3;     // sH1 h-chunk swizzle (row&7 == ln&7)

    // ---- register-resident weight B-fragments ----
    bf16x8 w1f[2][4];                   // W' frags
    #pragma unroll
    for (int kf = 0; kf < 2; ++kf)
        #pragma unroll
        for (int et = 0; et < 4; ++et)
            #pragma unroll
            for (int ii = 0; ii < 8; ++ii)
                w1f[kf][et][ii] = (__bf16)Wp[(kf*32 + lg*8 + ii)*256 + Ew + et*16 + ln];
    bf16x8 w2f[8];
    #pragma unroll
    for (int kf = 0; kf < 8; ++kf)
        #pragma unroll
        for (int ii = 0; ii < 8; ++ii)
            w2f[kf][ii] = (__bf16)attn_w2[(kf*32 + lg*8 + ii)*64 + dch];
    bf16x8 pwfw[2];                     // pos_w2 frags, this wave's d-slice only
    #pragma unroll
    for (int kf = 0; kf < 2; ++kf)
        #pragma unroll
        for (int ii = 0; ii < 8; ++ii)
            pwfw[kf][ii] = (__bf16)pos_w2[(kf*32 + lg*8 + ii)*64 + dch];

    float Q1b[4];
    #pragma unroll
    for (int et = 0; et < 4; ++et) Q1b[et] = Q1[blk*256 + Ew + et*16 + ln];
    const float pb2v = pos_b2[dch];
    const float b2v  = attn_b2[dch];

    const unsigned sHTb = (unsigned)(unsigned long long)&sHT[0][0][0][0];

    float mrun = -1e30f, srun = 0.f, arun = 0.f;

    // ---- stage A: h1 MLP only (no MFMA, no staging loads) ----
    auto stageA = [&](int j0a){
        const int bufa = (j0a >> 6) & 1;
        const float* pj = &pos[(b*512 + j0a + w*16 + ln)*3];
        const float r0 = sPOSI[0] - pj[0];
        const float r1 = sPOSI[1] - pj[1];
        const float r2 = sPOSI[2] - pj[2];
        #pragma unroll
        for (int kf = 0; kf < 2; ++kf){
            const int hb = kf*32 + lg*8;
            f32x4 wa0 = *(const f32x4*)&sPW1[      hb],   wa1 = *(const f32x4*)&sPW1[      hb+4];
            f32x4 wb0 = *(const f32x4*)&sPW1[ 64 + hb],   wb1 = *(const f32x4*)&sPW1[ 64 + hb+4];
            f32x4 wc0 = *(const f32x4*)&sPW1[128 + hb],   wc1 = *(const f32x4*)&sPW1[128 + hb+4];
            f32x4 bb0 = *(const f32x4*)&sPB1[      hb],   bb1 = *(const f32x4*)&sPB1[      hb+4];
            bf16x8 h1f;
            #pragma unroll
            for (int ii = 0; ii < 4; ++ii){
                float hv0 = bb0[ii] + r0*wa0[ii] + r1*wb0[ii] + r2*wc0[ii];
                float hv1 = bb1[ii] + r0*wa1[ii] + r1*wb1[ii] + r2*wc1[ii];
                h1f[ii]   = (__bf16)fmaxf(hv0, 0.f);
                h1f[ii+4] = (__bf16)fmaxf(hv1, 0.f);
            }
            *(bf16x8*)&sH1[bufa][w*16 + ln][hb ^ swzA] = h1f;
        }
    };

    __syncthreads();
    stageA(0);

    #pragma unroll 1
    for (int t = 0; t < 8; ++t){
        const int j0  = t << 6;
        const int buf = t & 1;
        __syncthreads();                                    // B1
        if (t < 7) stageA(j0 + 64);                         // -> sH1[buf^1]
        #pragma unroll 1
        for (int hb = 0; hb < 2; ++hb){
            // ============== stage B half: GEMM1' ======================
            #pragma unroll
            for (int jj = 0; jj < 2; ++jj){
                const int jrow = hb*32 + jj*16;
                const bf16x8 af0 = *(const bf16x8*)&sH1[buf][jrow + ln][(     lg*8) ^ swzA];
                const bf16x8 af1 = *(const bf16x8*)&sH1[buf][jrow + ln][(32 + lg*8) ^ swzA];
                float kw[4][4];
                #pragma unroll
                for (int et = 0; et < 4; ++et)
                    #pragma unroll
                    for (int ri = 0; ri < 4; ++ri)
                        kw[et][ri] = K1[(b*512 + j0 + jrow + lg*4 + ri)*256 + Ew + et*16 + ln];
                f32x4 accs[4];
                #pragma unroll
                for (int et = 0; et < 4; ++et){
                    f32x4 ci = {Q1b[et]-kw[et][0], Q1b[et]-kw[et][1],
                                Q1b[et]-kw[et][2], Q1b[et]-kw[et][3]};
                    accs[et] = ci;
                }
                __builtin_amdgcn_s_setprio(1);
                #pragma unroll
                for (int et = 0; et < 4; ++et)
                    accs[et] = __builtin_amdgcn_mfma_f32_16x16x32_bf16(af0, w1f[0][et], accs[et], 0, 0, 0);
                #pragma unroll
                for (int et = 0; et < 4; ++et)
                    accs[et] = __builtin_amdgcn_mfma_f32_16x16x32_bf16(af1, w1f[1][et], accs[et], 0, 0, 0);
                __builtin_amdgcn_s_setprio(0);
                #pragma unroll
                for (int et = 0; et < 4; ++et){
                    bf16x4 hp;
                    #pragma unroll
                    for (int ri = 0; ri < 4; ++ri) hp[ri] = (__bf16)fmaxf(accs[et][ri], 0.f);
                    *(bf16x4*)&sHT[w*16 + et*4 + (ln>>2)][jj][ln&3][lg*4] = hp;
                }
            }
            __syncthreads();                                // H half ready
            // ============== stage C half: GEMM2 + rpe + softmax =======
            #pragma unroll
            for (int jj = 0; jj < 2; ++jj){
                const int jrow = hb*32 + jj*16;
                float vvv[4];
                #pragma unroll
                for (int ri = 0; ri < 4; ++ri)
                    vvv[ri] = vp[(b*512 + j0 + jrow + lg*4 + ri)*64 + dch];
                const bf16x8 ra0 = *(const bf16x8*)&sH1[buf][jrow + ln][(     lg*8) ^ swzA];
                const bf16x8 ra1 = *(const bf16x8*)&sH1[buf][jrow + ln][(32 + lg*8) ^ swzA];
                u32x2 h1a[8];
                #pragma unroll
                for (int kf = 0; kf < 4; ++kf){
                    h1a[kf*2]   = tr_read(sHTb + 2u*(((8*kf + 2*lg    )*2 + jj)*64) + ln*8);
                    h1a[kf*2+1] = tr_read(sHTb + 2u*(((8*kf + 2*lg + 1)*2 + jj)*64) + ln*8);
                }
                asm volatile("s_waitcnt lgkmcnt(8)" ::: "memory");
                __builtin_amdgcn_sched_barrier(0);
                f32x4 rc = {pb2v, pb2v, pb2v, pb2v};        // rpe (for v2)
                rc = __builtin_amdgcn_mfma_f32_16x16x32_bf16(ra0, pwfw[0], rc, 0, 0, 0);
                rc = __builtin_amdgcn_mfma_f32_16x16x32_bf16(ra1, pwfw[1], rc, 0, 0, 0);
                u32x2 h1b[8];
                #pragma unroll
                for (int kf = 4; kf < 8; ++kf){
                    h1b[(kf-4)*2]   = tr_read(sHTb + 2u*(((8*kf + 2*lg    )*2 + jj)*64) + ln*8);
                    h1b[(kf-4)*2+1] = tr_read(sHTb + 2u*(((8*kf + 2*lg + 1)*2 + jj)*64) + ln*8);
                }
                asm volatile("s_waitcnt lgkmcnt(8)" ::: "memory");
                __builtin_amdgcn_sched_barrier(0);
                f32x4 a0 = {b2v, b2v, b2v, b2v};
                f32x4 a1 = {0.f, 0.f, 0.f, 0.f};
                __builtin_amdgcn_s_setprio(1);
                a0 = __builtin_amdgcn_mfma_f32_16x16x32_bf16(frag_cat(h1a[0], h1a[1]), w2f[0], a0, 0, 0, 0);
                a1 = __builtin_amdgcn_mfma_f32_16x16x32_bf16(frag_cat(h1a[2], h1a[3]), w2f[1], a1, 0, 0, 0);
                a0 = __builtin_amdgcn_mfma_f32_16x16x32_bf16(frag_cat(h1a[4], h1a[5]), w2f[2], a0, 0, 0, 0);
                a1 = __builtin_amdgcn_mfma_f32_16x16x32_bf16(frag_cat(h1a[6], h1a[7]), w2f[3], a1, 0, 0, 0);
                __builtin_amdgcn_s_setprio(0);
                asm volatile("s_waitcnt lgkmcnt(0)" ::: "memory");
                __builtin_amdgcn_sched_barrier(0);
                __builtin_amdgcn_s_setprio(1);
                a0 = __builtin_amdgcn_mfma_f32_16x16x32_bf16(frag_cat(h1b[0], h1b[1]), w2f[4], a0, 0, 0, 0);
                a1 = __builtin_amdgcn_mfma_f32_16x16x32_bf16(frag_cat(h1b[2], h1b[3]), w2f[5], a1, 0, 0, 0);
                a0 = __builtin_amdgcn_mfma_f32_16x16x32_bf16(frag_cat(h1b[4], h1b[5]), w2f[6], a0, 0, 0, 0);
                a1 = __builtin_amdgcn_mfma_f32_16x16x32_bf16(frag_cat(h1b[6], h1b[7]), w2f[7], a1, 0, 0, 0);
                __builtin_amdgcn_s_setprio(0);
                const f32x4 acc = a0 + a1;
                float tmax = fmaxf(fmaxf(acc[0], acc[1]), fmaxf(acc[2], acc[3]));
                tmax = fmaxf(tmax, __shfl_xor(tmax, 16));
                tmax = fmaxf(tmax, __shfl_xor(tmax, 32));
                const float mnew  = fmaxf(mrun, tmax);
                const float scale = __expf(mrun - mnew);
                srun *= scale; arun *= scale; mrun = mnew;
                #pragma unroll
                for (int ri = 0; ri < 4; ++ri){
                    const float p = __expf(acc[ri] - mnew);
                    srun += p;
                    arun += p * (vvv[ri] + rc[ri]);
                }
            }
            if (hb == 0) __syncthreads();                   // WAR: sHT reuse
        }
        // loop top's B1 covers: sH1[buf] WAR vs A(t+2), sHT WAR vs Bhalf0(t+1)
    }

    arun += __shfl_xor(arun, 16); arun += __shfl_xor(arun, 32);
    srun += __shfl_xor(srun, 16); srun += __shfl_xor(srun, 32);
    if (lg == 0) sAGG[dch] = arun / srun;
    __syncthreads();

    if (tid < 64){
        float a = fin_b[tid] + x1p[blk*64 + tid];
        #pragma unroll 16
        for (int c = 0; c < 64; ++c) a += sAGG[c] * fin_w[c*64 + tid];
        out[blk*64 + tid] = a;
    }
}

// ---------------------------------------------------------------------------
extern "C" void kernel_launch(void* const* d_in, const int* in_sizes, int n_in,
                              void* d_out, int out_size, void* d_ws, size_t ws_size,
                              hipStream_t stream)
{
    const float* x       = (const float*)d_in[0];
    const float* pos     = (const float*)d_in[1];
    const float* prev_w  = (const float*)d_in[2];
    const float* prev_b  = (const float*)d_in[3];
    const float* q_w     = (const float*)d_in[4];
    const float* k_w     = (const float*)d_in[5];
    const float* v_w     = (const float*)d_in[6];
    const float* pos_w1  = (const float*)d_in[7];
    const float* pos_b1  = (const float*)d_in[8];
    const float* pos_w2  = (const float*)d_in[9];
    const float* pos_b2  = (const float*)d_in[10];
    const float* attn_w1 = (const float*)d_in[11];
    const float* attn_b1 = (const float*)d_in[12];
    const float* attn_w2 = (const float*)d_in[13];
    const float* attn_b2 = (const float*)d_in[14];
    const float* fin_w   = (const float*)d_in[15];
    const float* fin_b   = (const float*)d_in[16];
    float* out = (float*)d_out;
    float* ws  = (float*)d_ws;

    ptb_pre<<<272, 256, 0, stream>>>(x, pos, prev_w, prev_b, q_w, k_w, v_w,
                                     pos_w2, attn_w1, attn_b1, ws, out);
    ptb_main<<<1024, 256, 0, stream>>>(pos, pos_w1, pos_b1, pos_w2, pos_b2,
                                       attn_w2, attn_b2, fin_w, fin_b, ws, out);
}

// Round 9
// 111.081 us; speedup vs baseline: 1.5965x; 1.0798x over previous
//
#include <hip/hip_runtime.h>

typedef __attribute__((ext_vector_type(4))) float f32x4;
typedef __attribute__((ext_vector_type(8))) __bf16 bf16x8;
typedef __attribute__((ext_vector_type(4))) __bf16 bf16x4;
typedef __attribute__((ext_vector_type(2))) unsigned int u32x2;

__device__ __forceinline__ u32x2 tr_read(unsigned int byte_addr){
    u32x2 d;
    asm volatile("ds_read_b64_tr_b16 %0, %1" : "=v"(d) : "v"(byte_addr));
    return d;
}
__device__ __forceinline__ bf16x8 frag_cat(u32x2 a, u32x2 b){
    union { u32x2 u[2]; bf16x8 f; } c; c.u[0] = a; c.u[1] = b; return c.f;
}

// ws layout (floats):
//   x1   @ 0       (65536)
//   vs   @ 65536   (65536)    v row-group-swizzled [row/4][64][4]  (row GLOBAL)
//   Q1   @ 131072  (262144)   q@attn_w1 + attn_b1   [1024][256]
//   K1s  @ 393216  (262144)   k@attn_w1 row-group-swizzled [row/4][256][4]
//   W'   @ 655360  (16384)    pos_w2@attn_w1        [64][256]
// total 671744 floats = 2.63 MB
// Swizzle [r/4][col][4]: lane(lg,ln) reads its 4 'ri' rows as ONE f32x4;
// ln lanes are 16B apart -> 256B contiguous per lg-group (wave-coalesced).
// NOTE (round-8 bug): consumer row-group index MUST include the batch
// offset b*128 (rows are global 0..1023). Missing it read batch-0 data
// for b=1 -> absmax 0.336 fail.

// ---------------------------------------------------------------------------
// Fused prologue: 272 blocks x 256.
//   blocks 0..255 : rows 4b..4b+3 : x1,q,k,v (phase 1, q/k/v stay in LDS),
//                   then Q1 row-major, K1s/vs swizzled (phase 2).
//                   pos passthrough to out.
//   blocks 256..271: W' = pos_w2 @ attn_w1.
// ---------------------------------------------------------------------------
__global__ void ptb_pre(const float* __restrict__ x,
                        const float* __restrict__ pos,
                        const float* __restrict__ prev_w,
                        const float* __restrict__ prev_b,
                        const float* __restrict__ q_w,
                        const float* __restrict__ k_w,
                        const float* __restrict__ v_w,
                        const float* __restrict__ pos_w2,
                        const float* __restrict__ attn_w1,
                        const float* __restrict__ attn_b1,
                        float* __restrict__ ws,
                        float* __restrict__ out)
{
    const int bid = blockIdx.x;
    const int tid = threadIdx.x;
    __shared__ float xr[256], x1r[256], qsh[256], ksh[256], vsh[256];

    float wcol[64];                       // attn_w1 column `tid`
    #pragma unroll
    for (int c = 0; c < 64; ++c) wcol[c] = attn_w1[c*256 + tid];

    if (bid >= 256){
        // W' = pos_w2 @ attn_w1  (rows 4(bid-256)..+3)
        xr[tid] = pos_w2[(bid - 256)*256 + tid];
        __syncthreads();
        float* Wp = ws + 655360;
        #pragma unroll
        for (int r = 0; r < 4; ++r){
            float s = 0.f;
            #pragma unroll 16
            for (int c = 0; c < 64; ++c) s += xr[r*64 + c] * wcol[c];
            Wp[((bid - 256)*4 + r)*256 + tid] = s;
        }
        return;
    }

    const int rr  = tid >> 6, d = tid & 63;
    const int row = bid*4 + rr;
    xr[tid] = x[row*64 + d];
    __syncthreads();
    float a = prev_b[d];
    #pragma unroll 16
    for (int c = 0; c < 64; ++c) a += xr[rr*64 + c] * prev_w[c*64 + d];
    x1r[tid] = a;
    ws[row*64 + d] = a;
    __syncthreads();
    float qv = 0.f, kv = 0.f, vv = 0.f;
    #pragma unroll 16
    for (int c = 0; c < 64; ++c){
        float t = x1r[rr*64 + c];
        qv += t * q_w[c*64 + d];
        kv += t * k_w[c*64 + d];
        vv += t * v_w[c*64 + d];
    }
    qsh[tid] = qv; ksh[tid] = kv; vsh[tid] = vv;
    if (tid < 12) out[65536 + bid*12 + tid] = pos[bid*12 + tid];
    __syncthreads();

    // vs store: coalesced transpose via LDS -> vs[bid*256 + d'*4 + r']
    ws[65536 + bid*256 + tid] = vsh[(tid & 3)*64 + (tid >> 2)];

    // phase 2: thread `tid` = hidden column e, all 4 rows of this block
    float* Q1  = ws + 131072;
    float* K1s = ws + 393216;
    const float bb = attn_b1[tid];
    float sq[4], sk[4];
    #pragma unroll
    for (int r = 0; r < 4; ++r){ sq[r] = bb; sk[r] = 0.f; }
    #pragma unroll 16
    for (int c = 0; c < 64; ++c){
        const float wv = wcol[c];
        #pragma unroll
        for (int r = 0; r < 4; ++r){
            sq[r] += qsh[r*64 + c] * wv;
            sk[r] += ksh[r*64 + c] * wv;
        }
    }
    #pragma unroll
    for (int r = 0; r < 4; ++r) Q1[(bid*4 + r)*256 + tid] = sq[r];
    f32x4 kvec = {sk[0], sk[1], sk[2], sk[3]};
    *(f32x4*)&K1s[bid*1024 + tid*4] = kvec;
}

// ---------------------------------------------------------------------------
// Kernel B: one block per (b,i). 4 waves. 64-j tiles, sHT halved (32-j).
// Per tile: [B1] A(t+1)->sH1[buf^1] + Bhalf0 ; [bar] Chalf0 ; [bar] Bhalf1 ;
//           [bar] Chalf1.
// GEMM1' : H = relu( h1relu @ W' + (Q1_i - K1_j) )
// rpe    : recomputed in stage C as 2 MFMAs (sH1 x pos_w2[:,dch-slice])
// K1s/vs consumed as coalesced f32x4 (cuts ~60 VMEM + ~120 addr VALU per
// tile per wave; VALUBusy was 54.7% = issue-bound on VALU).
// LDS 34KB, VGPR must stay <=128 for 4 waves/SIMD (m69: halve at 128).
// NO launch-bounds min-waves pin (round-1: forced VGPR 84 + spills).
// ---------------------------------------------------------------------------
__global__ __launch_bounds__(256) void ptb_main(
    const float* __restrict__ pos,
    const float* __restrict__ pos_w1, const float* __restrict__ pos_b1,
    const float* __restrict__ pos_w2, const float* __restrict__ pos_b2,
    const float* __restrict__ attn_w2, const float* __restrict__ attn_b2,
    const float* __restrict__ fin_w, const float* __restrict__ fin_b,
    const float* __restrict__ ws, float* __restrict__ out)
{
    const int blk = blockIdx.x;
    const int b   = blk >> 9;
    const int i   = blk & 511;
    const int tid = threadIdx.x;
    const int w   = tid >> 6;
    const int l   = tid & 63;
    const int lg  = l >> 4;
    const int ln  = l & 15;

    // h1 tile (post-relu), XOR-swizzled 16B chunks: [buf][j][h ^ ((j&7)<<3)]
    __shared__ __bf16 sH1[2][64][64];            // 16 KB
    // H^T half-tile for tr_read: [es=e/4][jj][er=e&3][jl=j&15]
    __shared__ __bf16 sHT[64][2][4][16];         // 16 KB
    __shared__ float sPW1[192], sPB1[64], sAGG[64], sPOSI[3];

    const float* x1p = ws;
    const float* vs  = ws + 65536;
    const float* Q1  = ws + 131072;
    const float* K1s = ws + 393216;
    const float* Wp  = ws + 655360;

    if (tid < 64) sPB1[tid] = pos_b1[tid];
    if (tid >= 64 && tid < 256) sPW1[tid - 64] = pos_w1[tid - 64];
    if (tid < 3) sPOSI[tid] = pos[(b*512 + i)*3 + tid];

    const int dch  = w*16 + ln;         // this lane's output channel (GEMM2)
    const int Ew   = w*64;              // this wave's hidden-col base (GEMM1')
    const int swzA = (ln & 7) << 3;     // sH1 h-chunk swizzle (row&7 == ln&7)

    // ---- register-resident weight B-fragments ----
    bf16x8 w1f[2][4];                   // W' frags
    #pragma unroll
    for (int kf = 0; kf < 2; ++kf)
        #pragma unroll
        for (int et = 0; et < 4; ++et)
            #pragma unroll
            for (int ii = 0; ii < 8; ++ii)
                w1f[kf][et][ii] = (__bf16)Wp[(kf*32 + lg*8 + ii)*256 + Ew + et*16 + ln];
    bf16x8 w2f[8];
    #pragma unroll
    for (int kf = 0; kf < 8; ++kf)
        #pragma unroll
        for (int ii = 0; ii < 8; ++ii)
            w2f[kf][ii] = (__bf16)attn_w2[(kf*32 + lg*8 + ii)*64 + dch];
    bf16x8 pwfw[2];                     // pos_w2 frags, this wave's d-slice only
    #pragma unroll
    for (int kf = 0; kf < 2; ++kf)
        #pragma unroll
        for (int ii = 0; ii < 8; ++ii)
            pwfw[kf][ii] = (__bf16)pos_w2[(kf*32 + lg*8 + ii)*64 + dch];

    float Q1b[4];
    #pragma unroll
    for (int et = 0; et < 4; ++et) Q1b[et] = Q1[blk*256 + Ew + et*16 + ln];
    const float pb2v = pos_b2[dch];
    const float b2v  = attn_b2[dch];

    const unsigned sHTb = (unsigned)(unsigned long long)&sHT[0][0][0][0];

    float mrun = -1e30f, srun = 0.f, arun = 0.f;

    // ---- stage A: h1 MLP only (no MFMA, no staging loads) ----
    auto stageA = [&](int j0a){
        const int bufa = (j0a >> 6) & 1;
        const float* pj = &pos[(b*512 + j0a + w*16 + ln)*3];
        const float r0 = sPOSI[0] - pj[0];
        const float r1 = sPOSI[1] - pj[1];
        const float r2 = sPOSI[2] - pj[2];
        #pragma unroll
        for (int kf = 0; kf < 2; ++kf){
            const int hb = kf*32 + lg*8;
            f32x4 wa0 = *(const f32x4*)&sPW1[      hb],   wa1 = *(const f32x4*)&sPW1[      hb+4];
            f32x4 wb0 = *(const f32x4*)&sPW1[ 64 + hb],   wb1 = *(const f32x4*)&sPW1[ 64 + hb+4];
            f32x4 wc0 = *(const f32x4*)&sPW1[128 + hb],   wc1 = *(const f32x4*)&sPW1[128 + hb+4];
            f32x4 bb0 = *(const f32x4*)&sPB1[      hb],   bb1 = *(const f32x4*)&sPB1[      hb+4];
            bf16x8 h1f;
            #pragma unroll
            for (int ii = 0; ii < 4; ++ii){
                float hv0 = bb0[ii] + r0*wa0[ii] + r1*wb0[ii] + r2*wc0[ii];
                float hv1 = bb1[ii] + r0*wa1[ii] + r1*wb1[ii] + r2*wc1[ii];
                h1f[ii]   = (__bf16)fmaxf(hv0, 0.f);
                h1f[ii+4] = (__bf16)fmaxf(hv1, 0.f);
            }
            *(bf16x8*)&sH1[bufa][w*16 + ln][hb ^ swzA] = h1f;
        }
    };

    __syncthreads();
    stageA(0);

    #pragma unroll 1
    for (int t = 0; t < 8; ++t){
        const int j0  = t << 6;
        const int buf = t & 1;
        __syncthreads();                                    // B1
        if (t < 7) stageA(j0 + 64);                         // -> sH1[buf^1]
        #pragma unroll 1
        for (int hb = 0; hb < 2; ++hb){
            // ============== stage B half: GEMM1' ======================
            #pragma unroll
            for (int jj = 0; jj < 2; ++jj){
                const int jrow = hb*32 + jj*16;
                const int krow = ((b*512 + j0 + jrow) >> 2) + lg;   // GLOBAL row group
                const bf16x8 af0 = *(const bf16x8*)&sH1[buf][jrow + ln][(     lg*8) ^ swzA];
                const bf16x8 af1 = *(const bf16x8*)&sH1[buf][jrow + ln][(32 + lg*8) ^ swzA];
                f32x4 accs[4];
                #pragma unroll
                for (int et = 0; et < 4; ++et){
                    const f32x4 kw4 = *(const f32x4*)&K1s[krow*1024 + (Ew + et*16 + ln)*4];
                    const f32x4 qv4 = {Q1b[et], Q1b[et], Q1b[et], Q1b[et]};
                    accs[et] = qv4 - kw4;
                }
                __builtin_amdgcn_s_setprio(1);
                #pragma unroll
                for (int et = 0; et < 4; ++et)
                    accs[et] = __builtin_amdgcn_mfma_f32_16x16x32_bf16(af0, w1f[0][et], accs[et], 0, 0, 0);
                #pragma unroll
                for (int et = 0; et < 4; ++et)
                    accs[et] = __builtin_amdgcn_mfma_f32_16x16x32_bf16(af1, w1f[1][et], accs[et], 0, 0, 0);
                __builtin_amdgcn_s_setprio(0);
                #pragma unroll
                for (int et = 0; et < 4; ++et){
                    bf16x4 hp;
                    #pragma unroll
                    for (int ri = 0; ri < 4; ++ri) hp[ri] = (__bf16)fmaxf(accs[et][ri], 0.f);
                    *(bf16x4*)&sHT[w*16 + et*4 + (ln>>2)][jj][ln&3][lg*4] = hp;
                }
            }
            __syncthreads();                                // H half ready
            // ============== stage C half: GEMM2 + rpe + softmax =======
            #pragma unroll
            for (int jj = 0; jj < 2; ++jj){
                const int jrow = hb*32 + jj*16;
                const int vrow = ((b*512 + j0 + jrow) >> 2) + lg;   // GLOBAL row group
                const f32x4 vv4 = *(const f32x4*)&vs[vrow*256 + dch*4];
                const bf16x8 ra0 = *(const bf16x8*)&sH1[buf][jrow + ln][(     lg*8) ^ swzA];
                const bf16x8 ra1 = *(const bf16x8*)&sH1[buf][jrow + ln][(32 + lg*8) ^ swzA];
                u32x2 h1a[8];
                #pragma unroll
                for (int kf = 0; kf < 4; ++kf){
                    h1a[kf*2]   = tr_read(sHTb + 2u*(((8*kf + 2*lg    )*2 + jj)*64) + ln*8);
                    h1a[kf*2+1] = tr_read(sHTb + 2u*(((8*kf + 2*lg + 1)*2 + jj)*64) + ln*8);
                }
                asm volatile("s_waitcnt lgkmcnt(8)" ::: "memory");
                __builtin_amdgcn_sched_barrier(0);
                f32x4 rc = {pb2v, pb2v, pb2v, pb2v};        // rpe (for v2)
                rc = __builtin_amdgcn_mfma_f32_16x16x32_bf16(ra0, pwfw[0], rc, 0, 0, 0);
                rc = __builtin_amdgcn_mfma_f32_16x16x32_bf16(ra1, pwfw[1], rc, 0, 0, 0);
                u32x2 h1b[8];
                #pragma unroll
                for (int kf = 4; kf < 8; ++kf){
                    h1b[(kf-4)*2]   = tr_read(sHTb + 2u*(((8*kf + 2*lg    )*2 + jj)*64) + ln*8);
                    h1b[(kf-4)*2+1] = tr_read(sHTb + 2u*(((8*kf + 2*lg + 1)*2 + jj)*64) + ln*8);
                }
                asm volatile("s_waitcnt lgkmcnt(8)" ::: "memory");
                __builtin_amdgcn_sched_barrier(0);
                f32x4 a0 = {b2v, b2v, b2v, b2v};
                f32x4 a1 = {0.f, 0.f, 0.f, 0.f};
                __builtin_amdgcn_s_setprio(1);
                a0 = __builtin_amdgcn_mfma_f32_16x16x32_bf16(frag_cat(h1a[0], h1a[1]), w2f[0], a0, 0, 0, 0);
                a1 = __builtin_amdgcn_mfma_f32_16x16x32_bf16(frag_cat(h1a[2], h1a[3]), w2f[1], a1, 0, 0, 0);
                a0 = __builtin_amdgcn_mfma_f32_16x16x32_bf16(frag_cat(h1a[4], h1a[5]), w2f[2], a0, 0, 0, 0);
                a1 = __builtin_amdgcn_mfma_f32_16x16x32_bf16(frag_cat(h1a[6], h1a[7]), w2f[3], a1, 0, 0, 0);
                __builtin_amdgcn_s_setprio(0);
                asm volatile("s_waitcnt lgkmcnt(0)" ::: "memory");
                __builtin_amdgcn_sched_barrier(0);
                __builtin_amdgcn_s_setprio(1);
                a0 = __builtin_amdgcn_mfma_f32_16x16x32_bf16(frag_cat(h1b[0], h1b[1]), w2f[4], a0, 0, 0, 0);
                a1 = __builtin_amdgcn_mfma_f32_16x16x32_bf16(frag_cat(h1b[2], h1b[3]), w2f[5], a1, 0, 0, 0);
                a0 = __builtin_amdgcn_mfma_f32_16x16x32_bf16(frag_cat(h1b[4], h1b[5]), w2f[6], a0, 0, 0, 0);
                a1 = __builtin_amdgcn_mfma_f32_16x16x32_bf16(frag_cat(h1b[6], h1b[7]), w2f[7], a1, 0, 0, 0);
                __builtin_amdgcn_s_setprio(0);
                const f32x4 acc = a0 + a1;
                float tmax = fmaxf(fmaxf(acc[0], acc[1]), fmaxf(acc[2], acc[3]));
                tmax = fmaxf(tmax, __shfl_xor(tmax, 16));
                tmax = fmaxf(tmax, __shfl_xor(tmax, 32));
                const float mnew  = fmaxf(mrun, tmax);
                const float scale = __expf(mrun - mnew);
                srun *= scale; arun *= scale; mrun = mnew;
                #pragma unroll
                for (int ri = 0; ri < 4; ++ri){
                    const float p = __expf(acc[ri] - mnew);
                    srun += p;
                    arun += p * (vv4[ri] + rc[ri]);
                }
            }
            if (hb == 0) __syncthreads();                   // WAR: sHT reuse
        }
        // loop top's B1 covers: sH1[buf] WAR vs A(t+2), sHT WAR vs Bhalf0(t+1)
    }

    arun += __shfl_xor(arun, 16); arun += __shfl_xor(arun, 32);
    srun += __shfl_xor(srun, 16); srun += __shfl_xor(srun, 32);
    if (lg == 0) sAGG[dch] = arun / srun;
    __syncthreads();

    if (tid < 64){
        float a = fin_b[tid] + x1p[blk*64 + tid];
        #pragma unroll 16
        for (int c = 0; c < 64; ++c) a += sAGG[c] * fin_w[c*64 + tid];
        out[blk*64 + tid] = a;
    }
}

// ---------------------------------------------------------------------------
extern "C" void kernel_launch(void* const* d_in, const int* in_sizes, int n_in,
                              void* d_out, int out_size, void* d_ws, size_t ws_size,
                              hipStream_t stream)
{
    const float* x       = (const float*)d_in[0];
    const float* pos     = (const float*)d_in[1];
    const float* prev_w  = (const float*)d_in[2];
    const float* prev_b  = (const float*)d_in[3];
    const float* q_w     = (const float*)d_in[4];
    const float* k_w     = (const float*)d_in[5];
    const float* v_w     = (const float*)d_in[6];
    const float* pos_w1  = (const float*)d_in[7];
    const float* pos_b1  = (const float*)d_in[8];
    const float* pos_w2  = (const float*)d_in[9];
    const float* pos_b2  = (const float*)d_in[10];
    const float* attn_w1 = (const float*)d_in[11];
    const float* attn_b1 = (const float*)d_in[12];
    const float* attn_w2 = (const float*)d_in[13];
    const float* attn_b2 = (const float*)d_in[14];
    const float* fin_w   = (const float*)d_in[15];
    const float* fin_b   = (const float*)d_in[16];
    float* out = (float*)d_out;
    float* ws  = (float*)d_ws;

    ptb_pre<<<272, 256, 0, stream>>>(x, pos, prev_w, prev_b, q_w, k_w, v_w,
                                     pos_w2, attn_w1, attn_b1, ws, out);
    ptb_main<<<1024, 256, 0, stream>>>(pos, pos_w1, pos_b1, pos_w2, pos_b2,
                                       attn_w2, attn_b2, fin_w, fin_b, ws, out);
}

// Round 10
// 110.675 us; speedup vs baseline: 1.6024x; 1.0037x over previous
//
#include <hip/hip_runtime.h>

typedef __attribute__((ext_vector_type(4))) float f32x4;
typedef __attribute__((ext_vector_type(8))) __bf16 bf16x8;
typedef __attribute__((ext_vector_type(4))) __bf16 bf16x4;
typedef __attribute__((ext_vector_type(2))) unsigned int u32x2;

// tr_read with compile-time offset folded into the DS immediate: removes the
// per-read address VALU (~100 VALU/tile/wave at 64 tr_reads/tile).
template<int OFF>
__device__ __forceinline__ u32x2 tr_read_o(unsigned base){
    u32x2 d;
    asm volatile("ds_read_b64_tr_b16 %0, %1 offset:%c2"
                 : "=v"(d) : "v"(base), "i"(OFF));
    return d;
}
__device__ __forceinline__ bf16x8 frag_cat(u32x2 a, u32x2 b){
    union { u32x2 u[2]; bf16x8 f; } c; c.u[0] = a; c.u[1] = b; return c.f;
}

// ws layout (floats):
//   x1   @ 0       (65536)
//   vs   @ 65536   (65536)    v row-group-swizzled [row/4][64][4]  (row GLOBAL)
//   Q1   @ 131072  (262144)   q@attn_w1 + attn_b1   [1024][256]
//   K1s  @ 393216  (262144)   k@attn_w1 row-group-swizzled [row/4][256][4]
//   W'   @ 655360  (16384)    pos_w2@attn_w1        [64][256]
// Swizzle [r/4][col][4]: lane(lg,ln) reads its 4 'ri' rows as ONE f32x4;
// consumer row-group index includes batch offset (round-8 bug).

// ---------------------------------------------------------------------------
// Fused prologue: 272 blocks x 256. (unchanged from round 9)
// ---------------------------------------------------------------------------
__global__ void ptb_pre(const float* __restrict__ x,
                        const float* __restrict__ pos,
                        const float* __restrict__ prev_w,
                        const float* __restrict__ prev_b,
                        const float* __restrict__ q_w,
                        const float* __restrict__ k_w,
                        const float* __restrict__ v_w,
                        const float* __restrict__ pos_w2,
                        const float* __restrict__ attn_w1,
                        const float* __restrict__ attn_b1,
                        float* __restrict__ ws,
                        float* __restrict__ out)
{
    const int bid = blockIdx.x;
    const int tid = threadIdx.x;
    __shared__ float xr[256], x1r[256], qsh[256], ksh[256], vsh[256];

    float wcol[64];                       // attn_w1 column `tid`
    #pragma unroll
    for (int c = 0; c < 64; ++c) wcol[c] = attn_w1[c*256 + tid];

    if (bid >= 256){
        // W' = pos_w2 @ attn_w1  (rows 4(bid-256)..+3)
        xr[tid] = pos_w2[(bid - 256)*256 + tid];
        __syncthreads();
        float* Wp = ws + 655360;
        #pragma unroll
        for (int r = 0; r < 4; ++r){
            float s = 0.f;
            #pragma unroll 16
            for (int c = 0; c < 64; ++c) s += xr[r*64 + c] * wcol[c];
            Wp[((bid - 256)*4 + r)*256 + tid] = s;
        }
        return;
    }

    const int rr  = tid >> 6, d = tid & 63;
    const int row = bid*4 + rr;
    xr[tid] = x[row*64 + d];
    __syncthreads();
    float a = prev_b[d];
    #pragma unroll 16
    for (int c = 0; c < 64; ++c) a += xr[rr*64 + c] * prev_w[c*64 + d];
    x1r[tid] = a;
    ws[row*64 + d] = a;
    __syncthreads();
    float qv = 0.f, kv = 0.f, vv = 0.f;
    #pragma unroll 16
    for (int c = 0; c < 64; ++c){
        float t = x1r[rr*64 + c];
        qv += t * q_w[c*64 + d];
        kv += t * k_w[c*64 + d];
        vv += t * v_w[c*64 + d];
    }
    qsh[tid] = qv; ksh[tid] = kv; vsh[tid] = vv;
    if (tid < 12) out[65536 + bid*12 + tid] = pos[bid*12 + tid];
    __syncthreads();

    // vs store: coalesced transpose via LDS -> vs[bid*256 + d'*4 + r']
    ws[65536 + bid*256 + tid] = vsh[(tid & 3)*64 + (tid >> 2)];

    // phase 2: thread `tid` = hidden column e, all 4 rows of this block
    float* Q1  = ws + 131072;
    float* K1s = ws + 393216;
    const float bb = attn_b1[tid];
    float sq[4], sk[4];
    #pragma unroll
    for (int r = 0; r < 4; ++r){ sq[r] = bb; sk[r] = 0.f; }
    #pragma unroll 16
    for (int c = 0; c < 64; ++c){
        const float wv = wcol[c];
        #pragma unroll
        for (int r = 0; r < 4; ++r){
            sq[r] += qsh[r*64 + c] * wv;
            sk[r] += ksh[r*64 + c] * wv;
        }
    }
    #pragma unroll
    for (int r = 0; r < 4; ++r) Q1[(bid*4 + r)*256 + tid] = sq[r];
    f32x4 kvec = {sk[0], sk[1], sk[2], sk[3]};
    *(f32x4*)&K1s[bid*1024 + tid*4] = kvec;
}

// ---------------------------------------------------------------------------
// Kernel B: one block per (b,i). 4 waves. 64-j tiles, sHT halved (32-j).
// Per tile: [B1] A(t+1)->sH1[buf^1] + Bhalf0 ; [bar] Chalf0 ; [bar] Bhalf1 ;
//           [bar] Chalf1.
// Round-10: (1) tr_read offsets folded into DS imm (trbase hoisted, zero
// per-read addr VALU); (2) rpe MFMA moved into stage B (af0/af1 already in
// regs -> stage C's ra0/ra1 re-reads deleted, -8 ds_read_b128/tile/wave);
// rcs[2] (8 VGPR) carried across the barrier. VGPR tripwire: must stay <=128.
// NO launch-bounds min-waves pin (round-1: forced VGPR 84 + spills).
// ---------------------------------------------------------------------------
__global__ __launch_bounds__(256) void ptb_main(
    const float* __restrict__ pos,
    const float* __restrict__ pos_w1, const float* __restrict__ pos_b1,
    const float* __restrict__ pos_w2, const float* __restrict__ pos_b2,
    const float* __restrict__ attn_w2, const float* __restrict__ attn_b2,
    const float* __restrict__ fin_w, const float* __restrict__ fin_b,
    const float* __restrict__ ws, float* __restrict__ out)
{
    const int blk = blockIdx.x;
    const int b   = blk >> 9;
    const int i   = blk & 511;
    const int tid = threadIdx.x;
    const int w   = tid >> 6;
    const int l   = tid & 63;
    const int lg  = l >> 4;
    const int ln  = l & 15;

    // h1 tile (post-relu), XOR-swizzled 16B chunks: [buf][j][h ^ ((j&7)<<3)]
    __shared__ __bf16 sH1[2][64][64];            // 16 KB
    // H^T half-tile for tr_read: [es=e/4][jj][er=e&3][jl=j&15]
    __shared__ __bf16 sHT[64][2][4][16];         // 16 KB
    __shared__ float sPW1[192], sPB1[64], sAGG[64], sPOSI[3];

    const float* x1p = ws;
    const float* vs  = ws + 65536;
    const float* Q1  = ws + 131072;
    const float* K1s = ws + 393216;
    const float* Wp  = ws + 655360;

    if (tid < 64) sPB1[tid] = pos_b1[tid];
    if (tid >= 64 && tid < 256) sPW1[tid - 64] = pos_w1[tid - 64];
    if (tid < 3) sPOSI[tid] = pos[(b*512 + i)*3 + tid];

    const int dch  = w*16 + ln;         // this lane's output channel (GEMM2)
    const int Ew   = w*64;              // this wave's hidden-col base (GEMM1')
    const int swzA = (ln & 7) << 3;     // sH1 h-chunk swizzle (row&7 == ln&7)

    // ---- register-resident weight B-fragments ----
    bf16x8 w1f[2][4];                   // W' frags
    #pragma unroll
    for (int kf = 0; kf < 2; ++kf)
        #pragma unroll
        for (int et = 0; et < 4; ++et)
            #pragma unroll
            for (int ii = 0; ii < 8; ++ii)
                w1f[kf][et][ii] = (__bf16)Wp[(kf*32 + lg*8 + ii)*256 + Ew + et*16 + ln];
    bf16x8 w2f[8];
    #pragma unroll
    for (int kf = 0; kf < 8; ++kf)
        #pragma unroll
        for (int ii = 0; ii < 8; ++ii)
            w2f[kf][ii] = (__bf16)attn_w2[(kf*32 + lg*8 + ii)*64 + dch];
    bf16x8 pwfw[2];                     // pos_w2 frags, this wave's d-slice only
    #pragma unroll
    for (int kf = 0; kf < 2; ++kf)
        #pragma unroll
        for (int ii = 0; ii < 8; ++ii)
            pwfw[kf][ii] = (__bf16)pos_w2[(kf*32 + lg*8 + ii)*64 + dch];

    float Q1b[4];
    #pragma unroll
    for (int et = 0; et < 4; ++et) Q1b[et] = Q1[blk*256 + Ew + et*16 + ln];
    const float pb2v = pos_b2[dch];
    const float b2v  = attn_b2[dch];

    const unsigned sHTb = (unsigned)(unsigned long long)&sHT[0][0][0][0];
    // per-lane tr_read base, loop-invariant: byte = (2lg)*256 + ln*8
    const unsigned trbase = sHTb + (unsigned)(lg*512 + ln*8);

    float mrun = -1e30f, srun = 0.f, arun = 0.f;

    // ---- stage A: h1 MLP only (no MFMA, no staging loads) ----
    auto stageA = [&](int j0a){
        const int bufa = (j0a >> 6) & 1;
        const float* pj = &pos[(b*512 + j0a + w*16 + ln)*3];
        const float r0 = sPOSI[0] - pj[0];
        const float r1 = sPOSI[1] - pj[1];
        const float r2 = sPOSI[2] - pj[2];
        #pragma unroll
        for (int kf = 0; kf < 2; ++kf){
            const int hb = kf*32 + lg*8;
            f32x4 wa0 = *(const f32x4*)&sPW1[      hb],   wa1 = *(const f32x4*)&sPW1[      hb+4];
            f32x4 wb0 = *(const f32x4*)&sPW1[ 64 + hb],   wb1 = *(const f32x4*)&sPW1[ 64 + hb+4];
            f32x4 wc0 = *(const f32x4*)&sPW1[128 + hb],   wc1 = *(const f32x4*)&sPW1[128 + hb+4];
            f32x4 bb0 = *(const f32x4*)&sPB1[      hb],   bb1 = *(const f32x4*)&sPB1[      hb+4];
            bf16x8 h1f;
            #pragma unroll
            for (int ii = 0; ii < 4; ++ii){
                float hv0 = bb0[ii] + r0*wa0[ii] + r1*wb0[ii] + r2*wc0[ii];
                float hv1 = bb1[ii] + r0*wa1[ii] + r1*wb1[ii] + r2*wc1[ii];
                h1f[ii]   = (__bf16)fmaxf(hv0, 0.f);
                h1f[ii+4] = (__bf16)fmaxf(hv1, 0.f);
            }
            *(bf16x8*)&sH1[bufa][w*16 + ln][hb ^ swzA] = h1f;
        }
    };

    __syncthreads();
    stageA(0);

    #pragma unroll 1
    for (int t = 0; t < 8; ++t){
        const int j0  = t << 6;
        const int buf = t & 1;
        __syncthreads();                                    // B1
        if (t < 7) stageA(j0 + 64);                         // -> sH1[buf^1]
        #pragma unroll 1
        for (int hb = 0; hb < 2; ++hb){
            f32x4 rcs[2];                                   // rpe, carried B->C
            // ============== stage B half: GEMM1' + rpe ================
            #pragma unroll
            for (int jj = 0; jj < 2; ++jj){
                const int jrow = hb*32 + jj*16;
                const int krow = ((b*512 + j0 + jrow) >> 2) + lg;   // GLOBAL row group
                const bf16x8 af0 = *(const bf16x8*)&sH1[buf][jrow + ln][(     lg*8) ^ swzA];
                const bf16x8 af1 = *(const bf16x8*)&sH1[buf][jrow + ln][(32 + lg*8) ^ swzA];
                f32x4 accs[4];
                #pragma unroll
                for (int et = 0; et < 4; ++et){
                    const f32x4 kw4 = *(const f32x4*)&K1s[krow*1024 + (Ew + et*16 + ln)*4];
                    const f32x4 qv4 = {Q1b[et], Q1b[et], Q1b[et], Q1b[et]};
                    accs[et] = qv4 - kw4;
                }
                __builtin_amdgcn_s_setprio(1);
                #pragma unroll
                for (int et = 0; et < 4; ++et)
                    accs[et] = __builtin_amdgcn_mfma_f32_16x16x32_bf16(af0, w1f[0][et], accs[et], 0, 0, 0);
                #pragma unroll
                for (int et = 0; et < 4; ++et)
                    accs[et] = __builtin_amdgcn_mfma_f32_16x16x32_bf16(af1, w1f[1][et], accs[et], 0, 0, 0);
                // rpe for v2 (was stage C's ra0/ra1 re-read; af already live)
                f32x4 rcv = {pb2v, pb2v, pb2v, pb2v};
                rcv = __builtin_amdgcn_mfma_f32_16x16x32_bf16(af0, pwfw[0], rcv, 0, 0, 0);
                rcv = __builtin_amdgcn_mfma_f32_16x16x32_bf16(af1, pwfw[1], rcv, 0, 0, 0);
                rcs[jj] = rcv;
                __builtin_amdgcn_s_setprio(0);
                #pragma unroll
                for (int et = 0; et < 4; ++et){
                    bf16x4 hp;
                    #pragma unroll
                    for (int ri = 0; ri < 4; ++ri) hp[ri] = (__bf16)fmaxf(accs[et][ri], 0.f);
                    *(bf16x4*)&sHT[w*16 + et*4 + (ln>>2)][jj][ln&3][lg*4] = hp;
                }
            }
            __syncthreads();                                // H half ready
            // ============== stage C half: GEMM2 + softmax =============
            #pragma unroll
            for (int jj = 0; jj < 2; ++jj){
                const int jrow = hb*32 + jj*16;
                const int vrow = ((b*512 + j0 + jrow) >> 2) + lg;   // GLOBAL row group
                const f32x4 vv4 = *(const f32x4*)&vs[vrow*256 + dch*4];
                const unsigned trb = trbase + (unsigned)(jj*128);
                u32x2 hh[16];
                if (jj == 0){
                    #define TR2(KF) \
                        hh[(KF)*2]   = tr_read_o<(KF)*2048      >(trb); \
                        hh[(KF)*2+1] = tr_read_o<(KF)*2048 + 256>(trb);
                    TR2(0) TR2(1) TR2(2) TR2(3) TR2(4) TR2(5) TR2(6) TR2(7)
                    #undef TR2
                } else {
                    #define TR2(KF) \
                        hh[(KF)*2]   = tr_read_o<(KF)*2048 + 128>(trb - 128u); \
                        hh[(KF)*2+1] = tr_read_o<(KF)*2048 + 384>(trb - 128u);
                    TR2(0) TR2(1) TR2(2) TR2(3) TR2(4) TR2(5) TR2(6) TR2(7)
                    #undef TR2
                }
                asm volatile("s_waitcnt lgkmcnt(8)" ::: "memory");
                __builtin_amdgcn_sched_barrier(0);
                f32x4 a0 = {b2v, b2v, b2v, b2v};
                f32x4 a1 = {0.f, 0.f, 0.f, 0.f};
                __builtin_amdgcn_s_setprio(1);
                a0 = __builtin_amdgcn_mfma_f32_16x16x32_bf16(frag_cat(hh[0], hh[1]), w2f[0], a0, 0, 0, 0);
                a1 = __builtin_amdgcn_mfma_f32_16x16x32_bf16(frag_cat(hh[2], hh[3]), w2f[1], a1, 0, 0, 0);
                a0 = __builtin_amdgcn_mfma_f32_16x16x32_bf16(frag_cat(hh[4], hh[5]), w2f[2], a0, 0, 0, 0);
                a1 = __builtin_amdgcn_mfma_f32_16x16x32_bf16(frag_cat(hh[6], hh[7]), w2f[3], a1, 0, 0, 0);
                __builtin_amdgcn_s_setprio(0);
                asm volatile("s_waitcnt lgkmcnt(0)" ::: "memory");
                __builtin_amdgcn_sched_barrier(0);
                __builtin_amdgcn_s_setprio(1);
                a0 = __builtin_amdgcn_mfma_f32_16x16x32_bf16(frag_cat(hh[8],  hh[9]),  w2f[4], a0, 0, 0, 0);
                a1 = __builtin_amdgcn_mfma_f32_16x16x32_bf16(frag_cat(hh[10], hh[11]), w2f[5], a1, 0, 0, 0);
                a0 = __builtin_amdgcn_mfma_f32_16x16x32_bf16(frag_cat(hh[12], hh[13]), w2f[6], a0, 0, 0, 0);
                a1 = __builtin_amdgcn_mfma_f32_16x16x32_bf16(frag_cat(hh[14], hh[15]), w2f[7], a1, 0, 0, 0);
                __builtin_amdgcn_s_setprio(0);
                const f32x4 acc = a0 + a1;
                const f32x4 rc  = rcs[jj];
                float tmax = fmaxf(fmaxf(acc[0], acc[1]), fmaxf(acc[2], acc[3]));
                tmax = fmaxf(tmax, __shfl_xor(tmax, 16));
                tmax = fmaxf(tmax, __shfl_xor(tmax, 32));
                const float mnew  = fmaxf(mrun, tmax);
                const float scale = __expf(mrun - mnew);
                srun *= scale; arun *= scale; mrun = mnew;
                #pragma unroll
                for (int ri = 0; ri < 4; ++ri){
                    const float p = __expf(acc[ri] - mnew);
                    srun += p;
                    arun += p * (vv4[ri] + rc[ri]);
                }
            }
            if (hb == 0) __syncthreads();                   // WAR: sHT reuse
        }
        // loop top's B1 covers: sH1[buf] WAR vs A(t+2), sHT WAR vs Bhalf0(t+1)
    }

    arun += __shfl_xor(arun, 16); arun += __shfl_xor(arun, 32);
    srun += __shfl_xor(srun, 16); srun += __shfl_xor(srun, 32);
    if (lg == 0) sAGG[dch] = arun / srun;
    __syncthreads();

    if (tid < 64){
        float a = fin_b[tid] + x1p[blk*64 + tid];
        #pragma unroll 16
        for (int c = 0; c < 64; ++c) a += sAGG[c] * fin_w[c*64 + tid];
        out[blk*64 + tid] = a;
    }
}

// ---------------------------------------------------------------------------
extern "C" void kernel_launch(void* const* d_in, const int* in_sizes, int n_in,
                              void* d_out, int out_size, void* d_ws, size_t ws_size,
                              hipStream_t stream)
{
    const float* x       = (const float*)d_in[0];
    const float* pos     = (const float*)d_in[1];
    const float* prev_w  = (const float*)d_in[2];
    const float* prev_b  = (const float*)d_in[3];
    const float* q_w     = (const float*)d_in[4];
    const float* k_w     = (const float*)d_in[5];
    const float* v_w     = (const float*)d_in[6];
    const float* pos_w1  = (const float*)d_in[7];
    const float* pos_b1  = (const float*)d_in[8];
    const float* pos_w2  = (const float*)d_in[9];
    const float* pos_b2  = (const float*)d_in[10];
    const float* attn_w1 = (const float*)d_in[11];
    const float* attn_b1 = (const float*)d_in[12];
    const float* attn_w2 = (const float*)d_in[13];
    const float* attn_b2 = (const float*)d_in[14];
    const float* fin_w   = (const float*)d_in[15];
    const float* fin_b   = (const float*)d_in[16];
    float* out = (float*)d_out;
    float* ws  = (float*)d_ws;

    ptb_pre<<<272, 256, 0, stream>>>(x, pos, prev_w, prev_b, q_w, k_w, v_w,
                                     pos_w2, attn_w1, attn_b1, ws, out);
    ptb_main<<<1024, 256, 0, stream>>>(pos, pos_w1, pos_b1, pos_w2, pos_b2,
                                       attn_w2, attn_b2, fin_w, fin_b, ws, out);
}

// Round 11
// 106.658 us; speedup vs baseline: 1.6627x; 1.0377x over previous
//
#include <hip/hip_runtime.h>

typedef __attribute__((ext_vector_type(4))) float f32x4;
typedef __attribute__((ext_vector_type(8))) __bf16 bf16x8;
typedef __attribute__((ext_vector_type(4))) __bf16 bf16x4;
typedef __attribute__((ext_vector_type(2))) unsigned int u32x2;

// tr_read with compile-time offset folded into the DS immediate.
template<int OFF>
__device__ __forceinline__ u32x2 tr_read_o(unsigned base){
    u32x2 d;
    asm volatile("ds_read_b64_tr_b16 %0, %1 offset:%c2"
                 : "=v"(d) : "v"(base), "i"(OFF));
    return d;
}
__device__ __forceinline__ bf16x8 frag_cat(u32x2 a, u32x2 b){
    union { u32x2 u[2]; bf16x8 f; } c; c.u[0] = a; c.u[1] = b; return c.f;
}

// ws layout (floats):
//   x1   @ 0       (65536)
//   vs   @ 65536   (65536)    v row-group-swizzled [row/4][64][4]  (row GLOBAL)
//   Q1   @ 131072  (262144)   q@attn_w1 + attn_b1   [1024][256]
//   K1s  @ 393216  (262144)   k@attn_w1 row-group-swizzled [row/4][256][4]
//   W'   @ 655360  (16384)    pos_w2@attn_w1        [64][256]

// ---------------------------------------------------------------------------
// Fused prologue: 272 blocks x 256. (unchanged from round 10)
// ---------------------------------------------------------------------------
__global__ void ptb_pre(const float* __restrict__ x,
                        const float* __restrict__ pos,
                        const float* __restrict__ prev_w,
                        const float* __restrict__ prev_b,
                        const float* __restrict__ q_w,
                        const float* __restrict__ k_w,
                        const float* __restrict__ v_w,
                        const float* __restrict__ pos_w2,
                        const float* __restrict__ attn_w1,
                        const float* __restrict__ attn_b1,
                        float* __restrict__ ws,
                        float* __restrict__ out)
{
    const int bid = blockIdx.x;
    const int tid = threadIdx.x;
    __shared__ float xr[256], x1r[256], qsh[256], ksh[256], vsh[256];

    float wcol[64];                       // attn_w1 column `tid`
    #pragma unroll
    for (int c = 0; c < 64; ++c) wcol[c] = attn_w1[c*256 + tid];

    if (bid >= 256){
        xr[tid] = pos_w2[(bid - 256)*256 + tid];
        __syncthreads();
        float* Wp = ws + 655360;
        #pragma unroll
        for (int r = 0; r < 4; ++r){
            float s = 0.f;
            #pragma unroll 16
            for (int c = 0; c < 64; ++c) s += xr[r*64 + c] * wcol[c];
            Wp[((bid - 256)*4 + r)*256 + tid] = s;
        }
        return;
    }

    const int rr  = tid >> 6, d = tid & 63;
    const int row = bid*4 + rr;
    xr[tid] = x[row*64 + d];
    __syncthreads();
    float a = prev_b[d];
    #pragma unroll 16
    for (int c = 0; c < 64; ++c) a += xr[rr*64 + c] * prev_w[c*64 + d];
    x1r[tid] = a;
    ws[row*64 + d] = a;
    __syncthreads();
    float qv = 0.f, kv = 0.f, vv = 0.f;
    #pragma unroll 16
    for (int c = 0; c < 64; ++c){
        float t = x1r[rr*64 + c];
        qv += t * q_w[c*64 + d];
        kv += t * k_w[c*64 + d];
        vv += t * v_w[c*64 + d];
    }
    qsh[tid] = qv; ksh[tid] = kv; vsh[tid] = vv;
    if (tid < 12) out[65536 + bid*12 + tid] = pos[bid*12 + tid];
    __syncthreads();

    // vs store: coalesced transpose via LDS -> vs[bid*256 + d'*4 + r']
    ws[65536 + bid*256 + tid] = vsh[(tid & 3)*64 + (tid >> 2)];

    float* Q1  = ws + 131072;
    float* K1s = ws + 393216;
    const float bb = attn_b1[tid];
    float sq[4], sk[4];
    #pragma unroll
    for (int r = 0; r < 4; ++r){ sq[r] = bb; sk[r] = 0.f; }
    #pragma unroll 16
    for (int c = 0; c < 64; ++c){
        const float wv = wcol[c];
        #pragma unroll
        for (int r = 0; r < 4; ++r){
            sq[r] += qsh[r*64 + c] * wv;
            sk[r] += ksh[r*64 + c] * wv;
        }
    }
    #pragma unroll
    for (int r = 0; r < 4; ++r) Q1[(bid*4 + r)*256 + tid] = sq[r];
    f32x4 kvec = {sk[0], sk[1], sk[2], sk[3]};
    *(f32x4*)&K1s[bid*1024 + tid*4] = kvec;
}

// ---------------------------------------------------------------------------
// Kernel B: one block per (b,i). 4 waves. 64-j tiles, sHT halved (32-j).
// Round-11:
// (1) sHT subtile RELOCATION: subtile (jj,E) at byte (jj*64+E)*144 (16B pad
//     per 128B subtile, dims reordered). Concurrent lg-groups in one tr_read
//     move from Δbank=0 (4-way alias, frozen 1.049e7 counter) to bank offsets
//     {0,8,16,24}. Subtile-INTERNAL layout untouched (pure base relocation,
//     bijective -> correctness preserved).
// (2) softmax deferred to once per C-half (accv[2]): 1 rescale+1 max-tree per
//     half instead of 2 (round-4's proven pattern). +8 VGPR.
// VGPR tripwire: must stay <=128. NO launch-bounds min-waves pin.
// ---------------------------------------------------------------------------
__global__ __launch_bounds__(256) void ptb_main(
    const float* __restrict__ pos,
    const float* __restrict__ pos_w1, const float* __restrict__ pos_b1,
    const float* __restrict__ pos_w2, const float* __restrict__ pos_b2,
    const float* __restrict__ attn_w2, const float* __restrict__ attn_b2,
    const float* __restrict__ fin_w, const float* __restrict__ fin_b,
    const float* __restrict__ ws, float* __restrict__ out)
{
    const int blk = blockIdx.x;
    const int b   = blk >> 9;
    const int i   = blk & 511;
    const int tid = threadIdx.x;
    const int w   = tid >> 6;
    const int l   = tid & 63;
    const int lg  = l >> 4;
    const int ln  = l & 15;

    // h1 tile (post-relu), XOR-swizzled 16B chunks: [buf][j][h ^ ((j&7)<<3)]
    __shared__ __bf16 sH1[2][64][64];            // 16 KB
    // H^T half-tile: 128 subtiles (jj*64+E) x 144B (128B data + 16B pad)
    __shared__ __align__(16) char sHT[18432];    // 18 KB
    __shared__ float sPW1[192], sPB1[64], sAGG[64], sPOSI[3];

    const float* x1p = ws;
    const float* vs  = ws + 65536;
    const float* Q1  = ws + 131072;
    const float* K1s = ws + 393216;
    const float* Wp  = ws + 655360;

    if (tid < 64) sPB1[tid] = pos_b1[tid];
    if (tid >= 64 && tid < 256) sPW1[tid - 64] = pos_w1[tid - 64];
    if (tid < 3) sPOSI[tid] = pos[(b*512 + i)*3 + tid];

    const int dch  = w*16 + ln;         // this lane's output channel (GEMM2)
    const int Ew   = w*64;              // this wave's hidden-col base (GEMM1')
    const int swzA = (ln & 7) << 3;     // sH1 h-chunk swizzle (row&7 == ln&7)

    // ---- register-resident weight B-fragments ----
    bf16x8 w1f[2][4];                   // W' frags
    #pragma unroll
    for (int kf = 0; kf < 2; ++kf)
        #pragma unroll
        for (int et = 0; et < 4; ++et)
            #pragma unroll
            for (int ii = 0; ii < 8; ++ii)
                w1f[kf][et][ii] = (__bf16)Wp[(kf*32 + lg*8 + ii)*256 + Ew + et*16 + ln];
    bf16x8 w2f[8];
    #pragma unroll
    for (int kf = 0; kf < 8; ++kf)
        #pragma unroll
        for (int ii = 0; ii < 8; ++ii)
            w2f[kf][ii] = (__bf16)attn_w2[(kf*32 + lg*8 + ii)*64 + dch];
    bf16x8 pwfw[2];                     // pos_w2 frags, this wave's d-slice only
    #pragma unroll
    for (int kf = 0; kf < 2; ++kf)
        #pragma unroll
        for (int ii = 0; ii < 8; ++ii)
            pwfw[kf][ii] = (__bf16)pos_w2[(kf*32 + lg*8 + ii)*64 + dch];

    float Q1b[4];
    #pragma unroll
    for (int et = 0; et < 4; ++et) Q1b[et] = Q1[blk*256 + Ew + et*16 + ln];
    const float pb2v = pos_b2[dch];
    const float b2v  = attn_b2[dch];

    const unsigned sHTb = (unsigned)(unsigned long long)&sHT[0];
    // per-lane tr_read base, loop-invariant: lg-group stride = 2 subtiles = 288B
    const unsigned trbase = sHTb + (unsigned)(lg*288 + ln*8);

    float mrun = -1e30f, srun = 0.f, arun = 0.f;

    // ---- stage A: h1 MLP only ----
    auto stageA = [&](int j0a){
        const int bufa = (j0a >> 6) & 1;
        const float* pj = &pos[(b*512 + j0a + w*16 + ln)*3];
        const float r0 = sPOSI[0] - pj[0];
        const float r1 = sPOSI[1] - pj[1];
        const float r2 = sPOSI[2] - pj[2];
        #pragma unroll
        for (int kf = 0; kf < 2; ++kf){
            const int hb = kf*32 + lg*8;
            f32x4 wa0 = *(const f32x4*)&sPW1[      hb],   wa1 = *(const f32x4*)&sPW1[      hb+4];
            f32x4 wb0 = *(const f32x4*)&sPW1[ 64 + hb],   wb1 = *(const f32x4*)&sPW1[ 64 + hb+4];
            f32x4 wc0 = *(const f32x4*)&sPW1[128 + hb],   wc1 = *(const f32x4*)&sPW1[128 + hb+4];
            f32x4 bb0 = *(const f32x4*)&sPB1[      hb],   bb1 = *(const f32x4*)&sPB1[      hb+4];
            bf16x8 h1f;
            #pragma unroll
            for (int ii = 0; ii < 4; ++ii){
                float hv0 = bb0[ii] + r0*wa0[ii] + r1*wb0[ii] + r2*wc0[ii];
                float hv1 = bb1[ii] + r0*wa1[ii] + r1*wb1[ii] + r2*wc1[ii];
                h1f[ii]   = (__bf16)fmaxf(hv0, 0.f);
                h1f[ii+4] = (__bf16)fmaxf(hv1, 0.f);
            }
            *(bf16x8*)&sH1[bufa][w*16 + ln][hb ^ swzA] = h1f;
        }
    };

    __syncthreads();
    stageA(0);

    #pragma unroll 1
    for (int t = 0; t < 8; ++t){
        const int j0  = t << 6;
        const int buf = t & 1;
        __syncthreads();                                    // B1
        if (t < 7) stageA(j0 + 64);                         // -> sH1[buf^1]
        #pragma unroll 1
        for (int hb = 0; hb < 2; ++hb){
            f32x4 rcs[2];                                   // rpe, carried B->C
            // ============== stage B half: GEMM1' + rpe ================
            #pragma unroll
            for (int jj = 0; jj < 2; ++jj){
                const int jrow = hb*32 + jj*16;
                const int krow = ((b*512 + j0 + jrow) >> 2) + lg;   // GLOBAL row group
                const bf16x8 af0 = *(const bf16x8*)&sH1[buf][jrow + ln][(     lg*8) ^ swzA];
                const bf16x8 af1 = *(const bf16x8*)&sH1[buf][jrow + ln][(32 + lg*8) ^ swzA];
                f32x4 accs[4];
                #pragma unroll
                for (int et = 0; et < 4; ++et){
                    const f32x4 kw4 = *(const f32x4*)&K1s[krow*1024 + (Ew + et*16 + ln)*4];
                    const f32x4 qv4 = {Q1b[et], Q1b[et], Q1b[et], Q1b[et]};
                    accs[et] = qv4 - kw4;
                }
                __builtin_amdgcn_s_setprio(1);
                #pragma unroll
                for (int et = 0; et < 4; ++et)
                    accs[et] = __builtin_amdgcn_mfma_f32_16x16x32_bf16(af0, w1f[0][et], accs[et], 0, 0, 0);
                #pragma unroll
                for (int et = 0; et < 4; ++et)
                    accs[et] = __builtin_amdgcn_mfma_f32_16x16x32_bf16(af1, w1f[1][et], accs[et], 0, 0, 0);
                f32x4 rcv = {pb2v, pb2v, pb2v, pb2v};
                rcv = __builtin_amdgcn_mfma_f32_16x16x32_bf16(af0, pwfw[0], rcv, 0, 0, 0);
                rcv = __builtin_amdgcn_mfma_f32_16x16x32_bf16(af1, pwfw[1], rcv, 0, 0, 0);
                rcs[jj] = rcv;
                __builtin_amdgcn_s_setprio(0);
                #pragma unroll
                for (int et = 0; et < 4; ++et){
                    bf16x4 hp;
                    #pragma unroll
                    for (int ri = 0; ri < 4; ++ri) hp[ri] = (__bf16)fmaxf(accs[et][ri], 0.f);
                    // subtile (jj, E = w*16+et*4+(ln>>2)) at (jj*64+E)*144
                    *(bf16x4*)(sHT + (jj*64 + w*16 + et*4 + (ln>>2))*144
                                   + (ln&3)*32 + lg*8) = hp;
                }
            }
            __syncthreads();                                // H half ready
            // ============== stage C half: GEMM2 + deferred softmax ====
            f32x4 accv[2], vvv[2];
            #pragma unroll
            for (int jj = 0; jj < 2; ++jj){
                const int vrow = ((b*512 + j0 + hb*32 + jj*16) >> 2) + lg;
                vvv[jj] = *(const f32x4*)&vs[vrow*256 + dch*4];
            }
            #pragma unroll
            for (int jj = 0; jj < 2; ++jj){
                const unsigned trb = trbase + (unsigned)(jj*9216);
                u32x2 hh[16];
                // subtile (jj, E=8kf+2lg+b): imm = kf*1152 + b*144
                #define TR2(KF) \
                    hh[(KF)*2]   = tr_read_o<(KF)*1152      >(trb); \
                    hh[(KF)*2+1] = tr_read_o<(KF)*1152 + 144>(trb);
                TR2(0) TR2(1) TR2(2) TR2(3) TR2(4) TR2(5) TR2(6) TR2(7)
                #undef TR2
                asm volatile("s_waitcnt lgkmcnt(8)" ::: "memory");
                __builtin_amdgcn_sched_barrier(0);
                f32x4 a0 = {b2v, b2v, b2v, b2v};
                f32x4 a1 = {0.f, 0.f, 0.f, 0.f};
                __builtin_amdgcn_s_setprio(1);
                a0 = __builtin_amdgcn_mfma_f32_16x16x32_bf16(frag_cat(hh[0], hh[1]), w2f[0], a0, 0, 0, 0);
                a1 = __builtin_amdgcn_mfma_f32_16x16x32_bf16(frag_cat(hh[2], hh[3]), w2f[1], a1, 0, 0, 0);
                a0 = __builtin_amdgcn_mfma_f32_16x16x32_bf16(frag_cat(hh[4], hh[5]), w2f[2], a0, 0, 0, 0);
                a1 = __builtin_amdgcn_mfma_f32_16x16x32_bf16(frag_cat(hh[6], hh[7]), w2f[3], a1, 0, 0, 0);
                __builtin_amdgcn_s_setprio(0);
                asm volatile("s_waitcnt lgkmcnt(0)" ::: "memory");
                __builtin_amdgcn_sched_barrier(0);
                __builtin_amdgcn_s_setprio(1);
                a0 = __builtin_amdgcn_mfma_f32_16x16x32_bf16(frag_cat(hh[8],  hh[9]),  w2f[4], a0, 0, 0, 0);
                a1 = __builtin_amdgcn_mfma_f32_16x16x32_bf16(frag_cat(hh[10], hh[11]), w2f[5], a1, 0, 0, 0);
                a0 = __builtin_amdgcn_mfma_f32_16x16x32_bf16(frag_cat(hh[12], hh[13]), w2f[6], a0, 0, 0, 0);
                a1 = __builtin_amdgcn_mfma_f32_16x16x32_bf16(frag_cat(hh[14], hh[15]), w2f[7], a1, 0, 0, 0);
                __builtin_amdgcn_s_setprio(0);
                accv[jj] = a0 + a1;
            }
            // one deferred softmax update per half (round-4 pattern)
            float tmax = fmaxf(fmaxf(fmaxf(accv[0][0], accv[0][1]),
                                     fmaxf(accv[0][2], accv[0][3])),
                               fmaxf(fmaxf(accv[1][0], accv[1][1]),
                                     fmaxf(accv[1][2], accv[1][3])));
            tmax = fmaxf(tmax, __shfl_xor(tmax, 16));
            tmax = fmaxf(tmax, __shfl_xor(tmax, 32));
            const float mnew  = fmaxf(mrun, tmax);
            const float scale = __expf(mrun - mnew);
            srun *= scale; arun *= scale; mrun = mnew;
            #pragma unroll
            for (int jj = 0; jj < 2; ++jj)
                #pragma unroll
                for (int ri = 0; ri < 4; ++ri){
                    const float p = __expf(accv[jj][ri] - mnew);
                    srun += p;
                    arun += p * (vvv[jj][ri] + rcs[jj][ri]);
                }
            if (hb == 0) __syncthreads();                   // WAR: sHT reuse
        }
        // loop top's B1 covers: sH1[buf] WAR vs A(t+2), sHT WAR vs Bhalf0(t+1)
    }

    arun += __shfl_xor(arun, 16); arun += __shfl_xor(arun, 32);
    srun += __shfl_xor(srun, 16); srun += __shfl_xor(srun, 32);
    if (lg == 0) sAGG[dch] = arun / srun;
    __syncthreads();

    if (tid < 64){
        float a = fin_b[tid] + x1p[blk*64 + tid];
        #pragma unroll 16
        for (int c = 0; c < 64; ++c) a += sAGG[c] * fin_w[c*64 + tid];
        out[blk*64 + tid] = a;
    }
}

// ---------------------------------------------------------------------------
extern "C" void kernel_launch(void* const* d_in, const int* in_sizes, int n_in,
                              void* d_out, int out_size, void* d_ws, size_t ws_size,
                              hipStream_t stream)
{
    const float* x       = (const float*)d_in[0];
    const float* pos     = (const float*)d_in[1];
    const float* prev_w  = (const float*)d_in[2];
    const float* prev_b  = (const float*)d_in[3];
    const float* q_w     = (const float*)d_in[4];
    const float* k_w     = (const float*)d_in[5];
    const float* v_w     = (const float*)d_in[6];
    const float* pos_w1  = (const float*)d_in[7];
    const float* pos_b1  = (const float*)d_in[8];
    const float* pos_w2  = (const float*)d_in[9];
    const float* pos_b2  = (const float*)d_in[10];
    const float* attn_w1 = (const float*)d_in[11];
    const float* attn_b1 = (const float*)d_in[12];
    const float* attn_w2 = (const float*)d_in[13];
    const float* attn_b2 = (const float*)d_in[14];
    const float* fin_w   = (const float*)d_in[15];
    const float* fin_b   = (const float*)d_in[16];
    float* out = (float*)d_out;
    float* ws  = (float*)d_ws;

    ptb_pre<<<272, 256, 0, stream>>>(x, pos, prev_w, prev_b, q_w, k_w, v_w,
                                     pos_w2, attn_w1, attn_b1, ws, out);
    ptb_main<<<1024, 256, 0, stream>>>(pos, pos_w1, pos_b1, pos_w2, pos_b2,
                                       attn_w2, attn_b2, fin_w, fin_b, ws, out);
}